// Round 9
// baseline (290.764 us; speedup 1.0000x reference)
//
#include <hip/hip_runtime.h>

// MiniTransformer: B=131072, T=8, D=32, H=64, V=27  (f32 in/out)
// R15: R14 + 2 rows per thread (shared LDS weight reads).
//   R14 post-mortem (WIN, 210->132us, VGPR 44, occ 42%): f16 MLP worked.
//   Remaining wall: LDS broadcast pipe. 620 ds_read_b128/row x ~41
//   wave-rows/CU x ~8-12cy = 85-125us/CU ~= the 132us wall (VALU only
//   64us; conflicts 0 => pure broadcast issue/return bandwidth).
//   Fix: thread computes rows (2k,2k+1) same t: weight quads read ONCE
//   per j / per v, applied to both rows => DS per row halves (620->310),
//   VALU total unchanged => predicted wall ~max(60, 65) = 75-95us.
//   Attention phases sequential per row (reuse f32 o[32] transient);
//   peak live ~90 VGPR => 4 waves/SIMD cap (16/CU keeps LDS saturated).
//   j-loop unroll 4, v-loop unroll 3 to hold the doubled body in icache.
//   TELLS: VGPR <= 128 and WRITE_SIZE ~108MB (no spills), else revert.

namespace {
constexpr int BTOT = 131072;     // 2^17
constexpr int T = 8;
constexpr int D = 32;
constexpr int H = 64;
constexpr int V = 27;
constexpr int NTOK = 27;
constexpr int NROW = T * NTOK;   // 216
constexpr float EPS = 1e-5f;

// ws layout (float offsets)
constexpr int WS_X  = 0;             // 216*32
constexpr int WS_Q  = 6912;
constexpr int WS_K  = 13824;
constexpr int WS_V  = 20736;
constexpr int WS_SC = 27648;         // 216*216 = 46656
constexpr int NSC   = NROW * NROW;
constexpr int WS_P  = WS_SC + NSC;   // 74304: prefix-output tables
constexpr int NPRE0 = 27;
constexpr int NPRE1 = 729;
constexpr int NPRE2 = 19683;
constexpr int NPRE  = NPRE0 + NPRE1 + NPRE2;   // 20439
constexpr size_t WS_NEED_BIG = (size_t)(WS_P + NPRE * V) * 4;  // ~2.45 MB

// two rows per thread
constexpr int MAIN_BLOCKS = (5 * BTOT / 2) / 256;      // 1280, exact
constexpr int PRE_PAIRS   = (NPRE + 1) / 2;            // 10220
constexpr int PRE_BLOCKS  = (PRE_PAIRS + 255) / 256;   // 40
} // namespace

typedef _Float16 h2 __attribute__((ext_vector_type(2)));
typedef _Float16 h8 __attribute__((ext_vector_type(8)));   // 16B -> ds_read_b128

#define FMA2(a, b, c) __builtin_elementwise_fma((a), (b), (c))

// acc += w(8 halves) . x(4x h2), 4 parallel chains
__device__ __forceinline__ void dot8(const h8 w, const h2* x,
                                     h2& a0, h2& a1, h2& a2, h2& a3) {
  a0 = FMA2(__builtin_shufflevector(w, w, 0, 1), x[0], a0);
  a1 = FMA2(__builtin_shufflevector(w, w, 2, 3), x[1], a1);
  a2 = FMA2(__builtin_shufflevector(w, w, 4, 5), x[2], a2);
  a3 = FMA2(__builtin_shufflevector(w, w, 6, 7), x[3], a3);
}
// y(4x h2) += hb * w(8 halves)
__device__ __forceinline__ void axpy8(const h2 hb, const h8 w, h2* y) {
  y[0] = FMA2(hb, __builtin_shufflevector(w, w, 0, 1), y[0]);
  y[1] = FMA2(hb, __builtin_shufflevector(w, w, 2, 3), y[1]);
  y[2] = FMA2(hb, __builtin_shufflevector(w, w, 4, 5), y[2]);
  y[3] = FMA2(hb, __builtin_shufflevector(w, w, 6, 7), y[3]);
}

// ---- kernel A: X/Q/K/V row tables, thread per (row,d) ----
__global__ __launch_bounds__(256) void build_rows_kernel(
    const float* __restrict__ tokE, const float* __restrict__ posE,
    const float* __restrict__ Wq, const float* __restrict__ Wk,
    const float* __restrict__ Wv, float* __restrict__ ws) {
  const int idx = blockIdx.x * 256 + threadIdx.x;
  if (idx >= NROW * D) return;
  const int row = idx >> 5, d = idx & 31;
  const int t = row / NTOK, tok = row % NTOK;
  float x[D];
#pragma unroll
  for (int g = 0; g < D / 4; ++g) {
    const float4 a = *(const float4*)(tokE + tok * D + 4 * g);
    const float4 c = *(const float4*)(posE + t * D + 4 * g);
    x[4 * g + 0] = a.x + c.x;
    x[4 * g + 1] = a.y + c.y;
    x[4 * g + 2] = a.z + c.z;
    x[4 * g + 3] = a.w + c.w;
  }
  float aq = 0.f, ak = 0.f, av = 0.f;
#pragma unroll
  for (int k = 0; k < D; ++k) {
    const float xv = x[k];
    aq = fmaf(xv, Wq[k * D + d], aq);
    ak = fmaf(xv, Wk[k * D + d], ak);
    av = fmaf(xv, Wv[k * D + d], av);
  }
  ws[WS_X + row * D + d] = x[d];
  ws[WS_Q + row * D + d] = aq;
  ws[WS_K + row * D + d] = ak;
  ws[WS_V + row * D + d] = av;
}

// ---- kernel B: score table SC[(t*27+tokt)*216 + s*27+toks] ----
__global__ __launch_bounds__(256) void build_sc_kernel(float* __restrict__ ws) {
  const int i = blockIdx.x * 256 + threadIdx.x;
  if (i >= NSC) return;
  const int qrow = i / NROW;
  const int j    = i - qrow * NROW;
  const float4* q = (const float4*)(ws + WS_Q + qrow * D);
  const float4* k = (const float4*)(ws + WS_K + j * D);
  float a = 0.f;
#pragma unroll
  for (int g = 0; g < D / 4; ++g) {
    const float4 qa = q[g], ka = k[g];
    a = fmaf(qa.x, ka.x, a);
    a = fmaf(qa.y, ka.y, a);
    a = fmaf(qa.z, ka.z, a);
    a = fmaf(qa.w, ka.w, a);
  }
  ws[WS_SC + i] = a;
}

// ---- f32 attention + LN1 -> packed f16 o2[16] (one row) ----
__device__ __forceinline__ void attn_ln1(
    const int t, const int* rowid, const float* __restrict__ ws, h2* o2) {
  const int qrow = rowid[t];
  const float* SC = ws + WS_SC + qrow * NROW;
  float sc[T];
#pragma unroll
  for (int s = 0; s < T; ++s)
    sc[s] = (s <= t) ? SC[rowid[s]] : -INFINITY;

  const float m01 = fmaxf(sc[0], sc[1]), m23 = fmaxf(sc[2], sc[3]);
  const float m45 = fmaxf(sc[4], sc[5]), m67 = fmaxf(sc[6], sc[7]);
  const float mx = fmaxf(fmaxf(m01, m23), fmaxf(m45, m67));

  float o[D];
#pragma unroll
  for (int d = 0; d < D; ++d) o[d] = 0.f;
  float den = 0.f;
#pragma unroll
  for (int s = 0; s < T; ++s) {
    if (s <= t) {
      const float ps = __expf(sc[s] - mx);
      den += ps;
      const float4* vr = (const float4*)(ws + WS_V + rowid[s] * D);
#pragma unroll
      for (int g = 0; g < D / 4; ++g) {
        const float4 v4 = vr[g];
        o[4 * g + 0] = fmaf(ps, v4.x, o[4 * g + 0]);
        o[4 * g + 1] = fmaf(ps, v4.y, o[4 * g + 1]);
        o[4 * g + 2] = fmaf(ps, v4.z, o[4 * g + 2]);
        o[4 * g + 3] = fmaf(ps, v4.w, o[4 * g + 3]);
      }
    }
  }
  const float inv = 1.f / den;
  {
    const float4* xr = (const float4*)(ws + WS_X + qrow * D);
#pragma unroll
    for (int g = 0; g < D / 4; ++g) {
      const float4 x4 = xr[g];
      o[4 * g + 0] = fmaf(o[4 * g + 0], inv, x4.x);
      o[4 * g + 1] = fmaf(o[4 * g + 1], inv, x4.y);
      o[4 * g + 2] = fmaf(o[4 * g + 2], inv, x4.z);
      o[4 * g + 3] = fmaf(o[4 * g + 3], inv, x4.w);
    }
  }

  float s1a = 0.f, s1b = 0.f, s1c = 0.f, s1d = 0.f;
#pragma unroll
  for (int d = 0; d < D; d += 4) {
    s1a += o[d]; s1b += o[d + 1]; s1c += o[d + 2]; s1d += o[d + 3];
  }
  const float mean = ((s1a + s1b) + (s1c + s1d)) * (1.f / D);
  float q0 = 0.f, q1 = 0.f, q2 = 0.f, q3 = 0.f;
#pragma unroll
  for (int d = 0; d < D; d += 4) {
    const float c0 = o[d] - mean, c1 = o[d + 1] - mean;
    const float c2 = o[d + 2] - mean, c3 = o[d + 3] - mean;
    q0 = fmaf(c0, c0, q0); q1 = fmaf(c1, c1, q1);
    q2 = fmaf(c2, c2, q2); q3 = fmaf(c3, c3, q3);
  }
  const float rr = rsqrtf(((q0 + q1) + (q2 + q3)) * (1.f / D) + EPS);
#pragma unroll
  for (int k = 0; k < 16; ++k) {
    o2[k] = h2{(_Float16)((o[2 * k] - mean) * rr),
               (_Float16)((o[2 * k + 1] - mean) * rr)};
  }
}

// ---- residual + LN2 (f32 stats), repack f16 in place ----
__device__ __forceinline__ void resid_ln2(h2* y2, const h2* o2) {
#pragma unroll
  for (int k = 0; k < 16; ++k) y2[k] = y2[k] + o2[k];
  float z[D];
#pragma unroll
  for (int k = 0; k < 16; ++k) {
    z[2 * k]     = (float)y2[k][0];
    z[2 * k + 1] = (float)y2[k][1];
  }
  float s1a = 0.f, s1b = 0.f, s1c = 0.f, s1d = 0.f;
#pragma unroll
  for (int d = 0; d < D; d += 4) {
    s1a += z[d]; s1b += z[d + 1]; s1c += z[d + 2]; s1d += z[d + 3];
  }
  const float mean = ((s1a + s1b) + (s1c + s1d)) * (1.f / D);
  float q0 = 0.f, q1 = 0.f, q2 = 0.f, q3 = 0.f;
#pragma unroll
  for (int d = 0; d < D; d += 4) {
    const float c0 = z[d] - mean, c1 = z[d + 1] - mean;
    const float c2 = z[d + 2] - mean, c3 = z[d + 3] - mean;
    q0 = fmaf(c0, c0, q0); q1 = fmaf(c1, c1, q1);
    q2 = fmaf(c2, c2, q2); q3 = fmaf(c3, c3, q3);
  }
  const float rr = rsqrtf(((q0 + q1) + (q2 + q3)) * (1.f / D) + EPS);
#pragma unroll
  for (int k = 0; k < 16; ++k) {
    y2[k] = h2{(_Float16)((z[2 * k] - mean) * rr),
               (_Float16)((z[2 * k + 1] - mean) * rr)};
  }
}

// ---- two rows, shared weight reads ----
__device__ __forceinline__ void compute_pair(
    const int tA, const int* ridA, float* __restrict__ dstA,
    const int tB, const int* ridB, float* __restrict__ dstB,
    const bool hasB,
    const float* __restrict__ ws,
    const h8* sW1T, const h8* sW2, const h8* sWoT) {
  h2 o2a[16], o2b[16];
  attn_ln1(tA, ridA, ws, o2a);
#pragma unroll
  for (int k = 0; k < 16; ++k) o2b[k] = h2{(_Float16)0.f, (_Float16)0.f};
  if (hasB) attn_ln1(tB, ridB, ws, o2b);

  h2 ya[16], yb[16];
#pragma unroll
  for (int k = 0; k < 16; ++k) {
    ya[k] = h2{(_Float16)0.f, (_Float16)0.f};
    yb[k] = h2{(_Float16)0.f, (_Float16)0.f};
  }
#pragma unroll 4
  for (int j = 0; j < H; ++j) {
    const h8 w0 = sW1T[j * 4 + 0], w1 = sW1T[j * 4 + 1];
    const h8 w2 = sW1T[j * 4 + 2], w3 = sW1T[j * 4 + 3];
    h2 a0 = h2{(_Float16)0.f, (_Float16)0.f};
    h2 a1 = a0, a2 = a0, a3 = a0;
    dot8(w0, &o2a[0], a0, a1, a2, a3);
    dot8(w1, &o2a[4], a0, a1, a2, a3);
    dot8(w2, &o2a[8], a0, a1, a2, a3);
    dot8(w3, &o2a[12], a0, a1, a2, a3);
    h2 b0 = h2{(_Float16)0.f, (_Float16)0.f};
    h2 b1 = b0, b2 = b0, b3 = b0;
    dot8(w0, &o2b[0], b0, b1, b2, b3);
    dot8(w1, &o2b[4], b0, b1, b2, b3);
    dot8(w2, &o2b[8], b0, b1, b2, b3);
    dot8(w3, &o2b[12], b0, b1, b2, b3);
    const h2 ha = (a0 + a1) + (a2 + a3);
    const h2 hbv = (b0 + b1) + (b2 + b3);
    _Float16 hja = (_Float16)(ha[0] + ha[1]);
    _Float16 hjb = (_Float16)(hbv[0] + hbv[1]);
    hja = (hja > (_Float16)0.f) ? hja : (_Float16)0.f;
    hjb = (hjb > (_Float16)0.f) ? hjb : (_Float16)0.f;
    const h2 hba = h2{hja, hja};
    const h2 hbb = h2{hjb, hjb};
    const h8 u0 = sW2[j * 4 + 0], u1 = sW2[j * 4 + 1];
    const h8 u2 = sW2[j * 4 + 2], u3 = sW2[j * 4 + 3];
    axpy8(hba, u0, &ya[0]);  axpy8(hbb, u0, &yb[0]);
    axpy8(hba, u1, &ya[4]);  axpy8(hbb, u1, &yb[4]);
    axpy8(hba, u2, &ya[8]);  axpy8(hbb, u2, &yb[8]);
    axpy8(hba, u3, &ya[12]); axpy8(hbb, u3, &yb[12]);
  }

  resid_ln2(ya, o2a);
  resid_ln2(yb, o2b);

#pragma unroll 3
  for (int vv = 0; vv < V; ++vv) {
    const h8 w0 = sWoT[vv * 4 + 0], w1 = sWoT[vv * 4 + 1];
    const h8 w2 = sWoT[vv * 4 + 2], w3 = sWoT[vv * 4 + 3];
    h2 a0 = h2{(_Float16)0.f, (_Float16)0.f};
    h2 a1 = a0, a2 = a0, a3 = a0;
    dot8(w0, &ya[0], a0, a1, a2, a3);
    dot8(w1, &ya[4], a0, a1, a2, a3);
    dot8(w2, &ya[8], a0, a1, a2, a3);
    dot8(w3, &ya[12], a0, a1, a2, a3);
    const h2 sa = (a0 + a1) + (a2 + a3);
    dstA[vv] = (float)(sa[0] + sa[1]);
    h2 b0 = h2{(_Float16)0.f, (_Float16)0.f};
    h2 b1 = b0, b2 = b0, b3 = b0;
    dot8(w0, &yb[0], b0, b1, b2, b3);
    dot8(w1, &yb[4], b0, b1, b2, b3);
    dot8(w2, &yb[8], b0, b1, b2, b3);
    dot8(w3, &yb[12], b0, b1, b2, b3);
    const h2 sb = (b0 + b1) + (b2 + b3);
    if (hasB) dstB[vv] = (float)(sb[0] + sb[1]);
  }
}

// ---- weight staging into LDS as f16 (W1, Wout transposed) ----
__device__ __forceinline__ void stage_weights(
    const float* __restrict__ W1, const float* __restrict__ W2,
    const float* __restrict__ Wo,
    h8* sW1T, h8* sW2, h8* sWoT) {
  _Float16* a = (_Float16*)sW1T;
  _Float16* b = (_Float16*)sW2;
  _Float16* c = (_Float16*)sWoT;
  const int tid = threadIdx.x;
  for (int i = tid; i < H * D; i += 256) {
    const int j = i >> 5, d = i & 31;           // i = j*32 + d
    a[i] = (_Float16)W1[d * H + j];             // W1T[j][d]
    b[i] = (_Float16)W2[i];                     // W2[j][d] (identity layout)
  }
  for (int i = tid; i < V * D; i += 256) {
    const int v = i >> 5, d = i & 31;           // i = v*32 + d
    c[i] = (_Float16)Wo[d * V + v];             // WoT[v][d]
  }
  __syncthreads();
}

// ---- prefix decode: i -> (t, rowid[8]) ----
__device__ __forceinline__ void decode_prefix(const int i, int& t, int* rowid) {
  int p;
  int t0 = 0, t1 = 0, t2 = 0;
  if (i < NPRE0)              { t = 0; p = i; t0 = p; }
  else if (i < NPRE0 + NPRE1) { t = 1; p = i - NPRE0; t0 = p / 27; t1 = p % 27; }
  else { t = 2; p = i - NPRE0 - NPRE1; t0 = p / 729;
         const int r = p % 729; t1 = r / 27; t2 = r % 27; }
  rowid[0] = t0; rowid[1] = 27 + t1; rowid[2] = 54 + t2;
  rowid[3] = 81; rowid[4] = 108; rowid[5] = 135; rowid[6] = 162; rowid[7] = 189;
}

// ---- kernel C: fused main (t in [3,8), 2 rows/thread) + prefix build ----
__global__ __launch_bounds__(256) void fused_main_kernel(
    const int* __restrict__ tokens,
    float* __restrict__ ws,
    const float* __restrict__ W1, const float* __restrict__ W2,
    const float* __restrict__ Wo, float* __restrict__ out) {
  __shared__ h8 sW1T[H * 4];   // 4 KB
  __shared__ h8 sW2[H * 4];    // 4 KB
  __shared__ h8 sWoT[V * 4];   // 1.7 KB
  stage_weights(W1, W2, Wo, sW1T, sW2, sWoT);

  if (blockIdx.x < MAIN_BLOCKS) {
    const int idx = blockIdx.x * 256 + threadIdx.x;   // [0, 5*BTOT/2), exact
    const int t = 3 + (idx >> 16);                    // block-uniform
    const int pair = idx & (BTOT / 2 - 1);
    const int b0 = pair << 1;                         // rows (b0,t),(b0+1,t)
    const int4 ta0 = *(const int4*)(tokens + b0 * T);
    const int4 tb0 = *(const int4*)(tokens + b0 * T + 4);
    const int4 ta1 = *(const int4*)(tokens + b0 * T + 8);
    const int4 tb1 = *(const int4*)(tokens + b0 * T + 12);
    int ridA[T], ridB[T];
    ridA[0] = ta0.x;       ridA[1] = 27 + ta0.y;
    ridA[2] = 54 + ta0.z;  ridA[3] = 81 + ta0.w;
    ridA[4] = 108 + tb0.x; ridA[5] = 135 + tb0.y;
    ridA[6] = 162 + tb0.z; ridA[7] = 189 + tb0.w;
    ridB[0] = ta1.x;       ridB[1] = 27 + ta1.y;
    ridB[2] = 54 + ta1.z;  ridB[3] = 81 + ta1.w;
    ridB[4] = 108 + tb1.x; ridB[5] = 135 + tb1.y;
    ridB[6] = 162 + tb1.z; ridB[7] = 189 + tb1.w;
    float* dstA = out + (long long)(b0 * T + t) * V;
    compute_pair(t, ridA, dstA, t, ridB, dstA + T * V, true,
                 ws, sW1T, sW2, sWoT);
  } else {
    const int g = (blockIdx.x - MAIN_BLOCKS) * 256 + threadIdx.x;
    if (g >= PRE_PAIRS) return;
    const int i0 = 2 * g;
    const int i1 = i0 + 1;
    const bool hasB = (i1 < NPRE);
    int tA, tB = 0;
    int ridA[T], ridB[T];
    decode_prefix(i0, tA, ridA);
    if (hasB) decode_prefix(i1, tB, ridB);
    else {
#pragma unroll
      for (int s = 0; s < T; ++s) ridB[s] = s * 27;
    }
    compute_pair(tA, ridA, ws + WS_P + i0 * V,
                 tB, ridB, ws + WS_P + i1 * V, hasB,
                 ws, sW1T, sW2, sWoT);
  }
}

// ---- kernel G: gather t<=2 rows; thread per (b, r), r in [0,81):
//      each b's three output rows are one contiguous 324B write run ----
__global__ __launch_bounds__(256) void gather_kernel(
    const int* __restrict__ tokens,
    const float* __restrict__ ws,
    float* __restrict__ out) {
  const int idx = blockIdx.x * 256 + threadIdx.x;   // [0, BTOT*81), exact
  const int b = idx / 81;
  const int r = idx - b * 81;
  const int t = r / 27;
  const int j = r - t * 27;
  const int t0 = tokens[b * T + 0];
  const int t1 = tokens[b * T + 1];
  const int t2 = tokens[b * T + 2];
  const int p01 = t0 * 27 + t1;
  const int pi = (t == 0) ? t0
               : (t == 1) ? (NPRE0 + p01)
                          : (NPRE0 + NPRE1 + p01 * 27 + t2);
  out[(long long)b * (T * V) + r] = ws[WS_P + pi * V + j];
}

// ---- fallback: all rows, 2 rows/thread (same b, t even/odd) ----
__global__ __launch_bounds__(256) void mini_kernel_all(
    const int* __restrict__ tokens,
    const float* __restrict__ ws,
    const float* __restrict__ W1, const float* __restrict__ W2,
    const float* __restrict__ Wo, float* __restrict__ out) {
  __shared__ h8 sW1T[H * 4];
  __shared__ h8 sW2[H * 4];
  __shared__ h8 sWoT[V * 4];
  stage_weights(W1, W2, Wo, sW1T, sW2, sWoT);

  const int gid = blockIdx.x * 256 + threadIdx.x;   // [0, BTOT*T/2)
  const int r0 = 2 * gid;                           // even => same b pair
  const int b = r0 >> 3;
  const int t = r0 & 7;
  const int4 ta = *(const int4*)(tokens + b * T);
  const int4 tb = *(const int4*)(tokens + b * T + 4);
  int rid[T];
  rid[0] = ta.x;       rid[1] = 27 + ta.y;
  rid[2] = 54 + ta.z;  rid[3] = 81 + ta.w;
  rid[4] = 108 + tb.x; rid[5] = 135 + tb.y;
  rid[6] = 162 + tb.z; rid[7] = 189 + tb.w;
  float* dstA = out + (long long)r0 * V;
  compute_pair(t, rid, dstA, t + 1, rid, dstA + V, true,
               ws, sW1T, sW2, sWoT);
}

extern "C" void kernel_launch(void* const* d_in, const int* in_sizes, int n_in,
                              void* d_out, int out_size, void* d_ws, size_t ws_size,
                              hipStream_t stream) {
  const int*   tokens  = (const int*)d_in[0];
  const float* tok_emb = (const float*)d_in[1];
  const float* pos_emb = (const float*)d_in[2];
  const float* Wq      = (const float*)d_in[3];
  const float* Wk      = (const float*)d_in[4];
  const float* Wv      = (const float*)d_in[5];
  const float* W1      = (const float*)d_in[6];
  const float* W2      = (const float*)d_in[7];
  const float* Wout    = (const float*)d_in[8];
  float* ws = (float*)d_ws;
  float* out = (float*)d_out;

  hipLaunchKernelGGL(build_rows_kernel, dim3((NROW * D + 255) / 256), dim3(256), 0,
                     stream, tok_emb, pos_emb, Wq, Wk, Wv, ws);
  hipLaunchKernelGGL(build_sc_kernel, dim3((NSC + 255) / 256), dim3(256), 0, stream, ws);

  if (ws_size >= WS_NEED_BIG) {
    hipLaunchKernelGGL(fused_main_kernel, dim3(MAIN_BLOCKS + PRE_BLOCKS), dim3(256), 0,
                       stream, tokens, ws, W1, W2, Wout, out);
    hipLaunchKernelGGL(gather_kernel, dim3((BTOT * 81) / 256), dim3(256), 0, stream,
                       tokens, ws, out);
  } else {
    hipLaunchKernelGGL(mini_kernel_all, dim3((BTOT * T / 2) / 256), dim3(256), 0,
                       stream, tokens, ws, W1, W2, Wout, out);
  }
}

// Round 10
// 280.054 us; speedup vs baseline: 1.0382x; 1.0382x over previous
//
#include <hip/hip_runtime.h>

// MiniTransformer: B=131072, T=8, D=32, H=64, V=27  (f32 in/out)
// R16: 2 rows/thread retry, register-disciplined.
//   R15 post-mortem (SPILLED): WRITE 108->219MB, VGPR 88, occ 18%,
//   160us. Peak live was ~115 (4-quad W1 + 4-quad W2 windows + dual
//   accums + double-inlined body) vs 88 allocated.
//   Model (validated by R14): fused_main is LDS-RETURN-BW bound:
//   675.8k rows x 9.9KB weights/row / 256 CU / ~100 B/cyc ~= 125us
//   ~= the 132us wall. VALU only ~64us. Halving bytes/row -> ~65us LDS.
//   R16 register discipline: (1) SINGLE compute_pair call site (branches
//   only fill t/rowid/dst); (2) y init = o2 (residual pre-add, commutes);
//   (3) 2-quad weight stepping in scoped blocks (<=8 weight VGPRs live);
//   (4) no hasB predication (odd prefix tail -> clamped duplicate row,
//   benign double store). Irreducible live: o2a/o2b/ya/yb=64 +8 w +8 acc.
//   TELLS: WRITE_SIZE ~108-118MB & dur < 132us, else pairing is refuted
//   -> revert R14. (R8 lesson: never use launch_bounds min-waves.)

namespace {
constexpr int BTOT = 131072;     // 2^17
constexpr int T = 8;
constexpr int D = 32;
constexpr int H = 64;
constexpr int V = 27;
constexpr int NTOK = 27;
constexpr int NROW = T * NTOK;   // 216
constexpr float EPS = 1e-5f;

// ws layout (float offsets)
constexpr int WS_X  = 0;             // 216*32
constexpr int WS_Q  = 6912;
constexpr int WS_K  = 13824;
constexpr int WS_V  = 20736;
constexpr int WS_SC = 27648;         // 216*216 = 46656
constexpr int NSC   = NROW * NROW;
constexpr int WS_P  = WS_SC + NSC;   // 74304: prefix-output tables
constexpr int NPRE0 = 27;
constexpr int NPRE1 = 729;
constexpr int NPRE2 = 19683;
constexpr int NPRE  = NPRE0 + NPRE1 + NPRE2;   // 20439
constexpr size_t WS_NEED_BIG = (size_t)(WS_P + NPRE * V) * 4;  // ~2.45 MB

// two rows per thread
constexpr int MAIN_BLOCKS = (5 * BTOT / 2) / 256;      // 1280, exact
constexpr int PRE_PAIRS   = (NPRE + 1) / 2;            // 10220
constexpr int PRE_BLOCKS  = (PRE_PAIRS + 255) / 256;   // 40
} // namespace

typedef _Float16 h2 __attribute__((ext_vector_type(2)));
typedef _Float16 h8 __attribute__((ext_vector_type(8)));   // 16B -> ds_read_b128

#define FMA2(a, b, c) __builtin_elementwise_fma((a), (b), (c))

// acc(4 chains) += w(8 halves) . x(4x h2)
__device__ __forceinline__ void dot8(const h8 w, const h2* x,
                                     h2& a0, h2& a1, h2& a2, h2& a3) {
  a0 = FMA2(__builtin_shufflevector(w, w, 0, 1), x[0], a0);
  a1 = FMA2(__builtin_shufflevector(w, w, 2, 3), x[1], a1);
  a2 = FMA2(__builtin_shufflevector(w, w, 4, 5), x[2], a2);
  a3 = FMA2(__builtin_shufflevector(w, w, 6, 7), x[3], a3);
}
// y(4x h2) += hb * w(8 halves)
__device__ __forceinline__ void axpy8(const h2 hb, const h8 w, h2* y) {
  y[0] = FMA2(hb, __builtin_shufflevector(w, w, 0, 1), y[0]);
  y[1] = FMA2(hb, __builtin_shufflevector(w, w, 2, 3), y[1]);
  y[2] = FMA2(hb, __builtin_shufflevector(w, w, 4, 5), y[2]);
  y[3] = FMA2(hb, __builtin_shufflevector(w, w, 6, 7), y[3]);
}

// ---- kernel A: X/Q/K/V row tables, thread per (row,d) ----
__global__ __launch_bounds__(256) void build_rows_kernel(
    const float* __restrict__ tokE, const float* __restrict__ posE,
    const float* __restrict__ Wq, const float* __restrict__ Wk,
    const float* __restrict__ Wv, float* __restrict__ ws) {
  const int idx = blockIdx.x * 256 + threadIdx.x;
  if (idx >= NROW * D) return;
  const int row = idx >> 5, d = idx & 31;
  const int t = row / NTOK, tok = row % NTOK;
  float x[D];
#pragma unroll
  for (int g = 0; g < D / 4; ++g) {
    const float4 a = *(const float4*)(tokE + tok * D + 4 * g);
    const float4 c = *(const float4*)(posE + t * D + 4 * g);
    x[4 * g + 0] = a.x + c.x;
    x[4 * g + 1] = a.y + c.y;
    x[4 * g + 2] = a.z + c.z;
    x[4 * g + 3] = a.w + c.w;
  }
  float aq = 0.f, ak = 0.f, av = 0.f;
#pragma unroll
  for (int k = 0; k < D; ++k) {
    const float xv = x[k];
    aq = fmaf(xv, Wq[k * D + d], aq);
    ak = fmaf(xv, Wk[k * D + d], ak);
    av = fmaf(xv, Wv[k * D + d], av);
  }
  ws[WS_X + row * D + d] = x[d];
  ws[WS_Q + row * D + d] = aq;
  ws[WS_K + row * D + d] = ak;
  ws[WS_V + row * D + d] = av;
}

// ---- kernel B: score table SC[(t*27+tokt)*216 + s*27+toks] ----
__global__ __launch_bounds__(256) void build_sc_kernel(float* __restrict__ ws) {
  const int i = blockIdx.x * 256 + threadIdx.x;
  if (i >= NSC) return;
  const int qrow = i / NROW;
  const int j    = i - qrow * NROW;
  const float4* q = (const float4*)(ws + WS_Q + qrow * D);
  const float4* k = (const float4*)(ws + WS_K + j * D);
  float a = 0.f;
#pragma unroll
  for (int g = 0; g < D / 4; ++g) {
    const float4 qa = q[g], ka = k[g];
    a = fmaf(qa.x, ka.x, a);
    a = fmaf(qa.y, ka.y, a);
    a = fmaf(qa.z, ka.z, a);
    a = fmaf(qa.w, ka.w, a);
  }
  ws[WS_SC + i] = a;
}

// ---- f32 attention + LN1 -> packed f16 o2[16] (one row) ----
__device__ __forceinline__ void attn_ln1(
    const int t, const int* rowid, const float* __restrict__ ws, h2* o2) {
  const int qrow = rowid[t];
  const float* SC = ws + WS_SC + qrow * NROW;
  float sc[T];
#pragma unroll
  for (int s = 0; s < T; ++s)
    sc[s] = (s <= t) ? SC[rowid[s]] : -INFINITY;

  const float m01 = fmaxf(sc[0], sc[1]), m23 = fmaxf(sc[2], sc[3]);
  const float m45 = fmaxf(sc[4], sc[5]), m67 = fmaxf(sc[6], sc[7]);
  const float mx = fmaxf(fmaxf(m01, m23), fmaxf(m45, m67));

  float o[D];
#pragma unroll
  for (int d = 0; d < D; ++d) o[d] = 0.f;
  float den = 0.f;
#pragma unroll
  for (int s = 0; s < T; ++s) {
    if (s <= t) {
      const float ps = __expf(sc[s] - mx);
      den += ps;
      const float4* vr = (const float4*)(ws + WS_V + rowid[s] * D);
#pragma unroll
      for (int g = 0; g < D / 4; ++g) {
        const float4 v4 = vr[g];
        o[4 * g + 0] = fmaf(ps, v4.x, o[4 * g + 0]);
        o[4 * g + 1] = fmaf(ps, v4.y, o[4 * g + 1]);
        o[4 * g + 2] = fmaf(ps, v4.z, o[4 * g + 2]);
        o[4 * g + 3] = fmaf(ps, v4.w, o[4 * g + 3]);
      }
    }
  }
  const float inv = 1.f / den;
  {
    const float4* xr = (const float4*)(ws + WS_X + qrow * D);
#pragma unroll
    for (int g = 0; g < D / 4; ++g) {
      const float4 x4 = xr[g];
      o[4 * g + 0] = fmaf(o[4 * g + 0], inv, x4.x);
      o[4 * g + 1] = fmaf(o[4 * g + 1], inv, x4.y);
      o[4 * g + 2] = fmaf(o[4 * g + 2], inv, x4.z);
      o[4 * g + 3] = fmaf(o[4 * g + 3], inv, x4.w);
    }
  }

  float s1a = 0.f, s1b = 0.f, s1c = 0.f, s1d = 0.f;
#pragma unroll
  for (int d = 0; d < D; d += 4) {
    s1a += o[d]; s1b += o[d + 1]; s1c += o[d + 2]; s1d += o[d + 3];
  }
  const float mean = ((s1a + s1b) + (s1c + s1d)) * (1.f / D);
  float q0 = 0.f, q1 = 0.f, q2 = 0.f, q3 = 0.f;
#pragma unroll
  for (int d = 0; d < D; d += 4) {
    const float c0 = o[d] - mean, c1 = o[d + 1] - mean;
    const float c2 = o[d + 2] - mean, c3 = o[d + 3] - mean;
    q0 = fmaf(c0, c0, q0); q1 = fmaf(c1, c1, q1);
    q2 = fmaf(c2, c2, q2); q3 = fmaf(c3, c3, q3);
  }
  const float rr = rsqrtf(((q0 + q1) + (q2 + q3)) * (1.f / D) + EPS);
#pragma unroll
  for (int k = 0; k < 16; ++k) {
    o2[k] = h2{(_Float16)((o[2 * k] - mean) * rr),
               (_Float16)((o[2 * k + 1] - mean) * rr)};
  }
}

// ---- LN2 in place on f16 y2 (f32 stats) ----
__device__ __forceinline__ void ln2_inplace(h2* y2) {
  float z[D];
#pragma unroll
  for (int k = 0; k < 16; ++k) {
    z[2 * k]     = (float)y2[k][0];
    z[2 * k + 1] = (float)y2[k][1];
  }
  float s1a = 0.f, s1b = 0.f, s1c = 0.f, s1d = 0.f;
#pragma unroll
  for (int d = 0; d < D; d += 4) {
    s1a += z[d]; s1b += z[d + 1]; s1c += z[d + 2]; s1d += z[d + 3];
  }
  const float mean = ((s1a + s1b) + (s1c + s1d)) * (1.f / D);
  float q0 = 0.f, q1 = 0.f, q2 = 0.f, q3 = 0.f;
#pragma unroll
  for (int d = 0; d < D; d += 4) {
    const float c0 = z[d] - mean, c1 = z[d + 1] - mean;
    const float c2 = z[d + 2] - mean, c3 = z[d + 3] - mean;
    q0 = fmaf(c0, c0, q0); q1 = fmaf(c1, c1, q1);
    q2 = fmaf(c2, c2, q2); q3 = fmaf(c3, c3, q3);
  }
  const float rr = rsqrtf(((q0 + q1) + (q2 + q3)) * (1.f / D) + EPS);
#pragma unroll
  for (int k = 0; k < 16; ++k) {
    y2[k] = h2{(_Float16)((z[2 * k] - mean) * rr),
               (_Float16)((z[2 * k + 1] - mean) * rr)};
  }
}

// ---- two rows, shared weight reads, 2-quad stepping ----
__device__ __forceinline__ void compute_pair(
    const int tA, const int* ridA, float* __restrict__ dstA,
    const int tB, const int* ridB, float* __restrict__ dstB,
    const float* __restrict__ ws,
    const h8* sW1T, const h8* sW2, const h8* sWoT) {
  h2 o2a[16], o2b[16];
  attn_ln1(tA, ridA, ws, o2a);
  attn_ln1(tB, ridB, ws, o2b);

  // y starts at o2 (residual pre-add; addition commutes with the j-sum)
  h2 ya[16], yb[16];
#pragma unroll
  for (int k = 0; k < 16; ++k) { ya[k] = o2a[k]; yb[k] = o2b[k]; }

#pragma unroll 4
  for (int j = 0; j < H; ++j) {
    h2 a0 = h2{(_Float16)0.f, (_Float16)0.f};
    h2 a1 = a0, a2 = a0, a3 = a0;
    h2 b0 = a0, b1 = a0, b2 = a0, b3 = a0;
    {
      const h8 w0 = sW1T[j * 4 + 0], w1 = sW1T[j * 4 + 1];
      dot8(w0, &o2a[0], a0, a1, a2, a3);
      dot8(w1, &o2a[4], a0, a1, a2, a3);
      dot8(w0, &o2b[0], b0, b1, b2, b3);
      dot8(w1, &o2b[4], b0, b1, b2, b3);
    }
    {
      const h8 w2 = sW1T[j * 4 + 2], w3 = sW1T[j * 4 + 3];
      dot8(w2, &o2a[8], a0, a1, a2, a3);
      dot8(w3, &o2a[12], a0, a1, a2, a3);
      dot8(w2, &o2b[8], b0, b1, b2, b3);
      dot8(w3, &o2b[12], b0, b1, b2, b3);
    }
    const h2 ha = (a0 + a1) + (a2 + a3);
    const h2 hb = (b0 + b1) + (b2 + b3);
    _Float16 hja = (_Float16)(ha[0] + ha[1]);
    _Float16 hjb = (_Float16)(hb[0] + hb[1]);
    hja = (hja > (_Float16)0.f) ? hja : (_Float16)0.f;
    hjb = (hjb > (_Float16)0.f) ? hjb : (_Float16)0.f;
    const h2 hba = h2{hja, hja};
    const h2 hbb = h2{hjb, hjb};
    {
      const h8 u0 = sW2[j * 4 + 0], u1 = sW2[j * 4 + 1];
      axpy8(hba, u0, &ya[0]);  axpy8(hbb, u0, &yb[0]);
      axpy8(hba, u1, &ya[4]);  axpy8(hbb, u1, &yb[4]);
    }
    {
      const h8 u2 = sW2[j * 4 + 2], u3 = sW2[j * 4 + 3];
      axpy8(hba, u2, &ya[8]);  axpy8(hbb, u2, &yb[8]);
      axpy8(hba, u3, &ya[12]); axpy8(hbb, u3, &yb[12]);
    }
  }

  ln2_inplace(ya);
  ln2_inplace(yb);

#pragma unroll 3
  for (int vv = 0; vv < V; ++vv) {
    h2 a0 = h2{(_Float16)0.f, (_Float16)0.f};
    h2 a1 = a0, a2 = a0, a3 = a0;
    h2 b0 = a0, b1 = a0, b2 = a0, b3 = a0;
    {
      const h8 w0 = sWoT[vv * 4 + 0], w1 = sWoT[vv * 4 + 1];
      dot8(w0, &ya[0], a0, a1, a2, a3);
      dot8(w1, &ya[4], a0, a1, a2, a3);
      dot8(w0, &yb[0], b0, b1, b2, b3);
      dot8(w1, &yb[4], b0, b1, b2, b3);
    }
    {
      const h8 w2 = sWoT[vv * 4 + 2], w3 = sWoT[vv * 4 + 3];
      dot8(w2, &ya[8], a0, a1, a2, a3);
      dot8(w3, &ya[12], a0, a1, a2, a3);
      dot8(w2, &yb[8], b0, b1, b2, b3);
      dot8(w3, &yb[12], b0, b1, b2, b3);
    }
    const h2 sa = (a0 + a1) + (a2 + a3);
    const h2 sb = (b0 + b1) + (b2 + b3);
    dstA[vv] = (float)(sa[0] + sa[1]);
    dstB[vv] = (float)(sb[0] + sb[1]);
  }
}

// ---- weight staging into LDS as f16 (W1, Wout transposed) ----
__device__ __forceinline__ void stage_weights(
    const float* __restrict__ W1, const float* __restrict__ W2,
    const float* __restrict__ Wo,
    h8* sW1T, h8* sW2, h8* sWoT) {
  _Float16* a = (_Float16*)sW1T;
  _Float16* b = (_Float16*)sW2;
  _Float16* c = (_Float16*)sWoT;
  const int tid = threadIdx.x;
  for (int i = tid; i < H * D; i += 256) {
    const int j = i >> 5, d = i & 31;           // i = j*32 + d
    a[i] = (_Float16)W1[d * H + j];             // W1T[j][d]
    b[i] = (_Float16)W2[i];                     // W2[j][d] (identity layout)
  }
  for (int i = tid; i < V * D; i += 256) {
    const int v = i >> 5, d = i & 31;           // i = v*32 + d
    c[i] = (_Float16)Wo[d * V + v];             // WoT[v][d]
  }
  __syncthreads();
}

// ---- prefix decode: i -> (t, rowid[8]) ----
__device__ __forceinline__ void decode_prefix(const int i, int& t, int* rowid) {
  int p;
  int t0 = 0, t1 = 0, t2 = 0;
  if (i < NPRE0)              { t = 0; p = i; t0 = p; }
  else if (i < NPRE0 + NPRE1) { t = 1; p = i - NPRE0; t0 = p / 27; t1 = p % 27; }
  else { t = 2; p = i - NPRE0 - NPRE1; t0 = p / 729;
         const int r = p % 729; t1 = r / 27; t2 = r % 27; }
  rowid[0] = t0; rowid[1] = 27 + t1; rowid[2] = 54 + t2;
  rowid[3] = 81; rowid[4] = 108; rowid[5] = 135; rowid[6] = 162; rowid[7] = 189;
}

// ---- kernel C: fused main (t in [3,8), 2 rows/thread) + prefix build ----
// Branches only FILL parameters; single compute_pair call site below.
__global__ __launch_bounds__(256) void fused_main_kernel(
    const int* __restrict__ tokens,
    float* __restrict__ ws,
    const float* __restrict__ W1, const float* __restrict__ W2,
    const float* __restrict__ Wo, float* __restrict__ out) {
  __shared__ h8 sW1T[H * 4];   // 4 KB
  __shared__ h8 sW2[H * 4];    // 4 KB
  __shared__ h8 sWoT[V * 4];   // 1.7 KB
  stage_weights(W1, W2, Wo, sW1T, sW2, sWoT);

  int tA, tB;
  int ridA[T], ridB[T];
  float *dstA, *dstB;

  if (blockIdx.x < MAIN_BLOCKS) {
    const int idx = blockIdx.x * 256 + threadIdx.x;   // [0, 5*BTOT/2), exact
    tA = 3 + (idx >> 16);                             // block-uniform
    tB = tA;
    const int pair = idx & (BTOT / 2 - 1);
    const int b0 = pair << 1;                         // rows (b0,t),(b0+1,t)
    const int4 ta0 = *(const int4*)(tokens + b0 * T);
    const int4 tb0 = *(const int4*)(tokens + b0 * T + 4);
    const int4 ta1 = *(const int4*)(tokens + b0 * T + 8);
    const int4 tb1 = *(const int4*)(tokens + b0 * T + 12);
    ridA[0] = ta0.x;       ridA[1] = 27 + ta0.y;
    ridA[2] = 54 + ta0.z;  ridA[3] = 81 + ta0.w;
    ridA[4] = 108 + tb0.x; ridA[5] = 135 + tb0.y;
    ridA[6] = 162 + tb0.z; ridA[7] = 189 + tb0.w;
    ridB[0] = ta1.x;       ridB[1] = 27 + ta1.y;
    ridB[2] = 54 + ta1.z;  ridB[3] = 81 + ta1.w;
    ridB[4] = 108 + tb1.x; ridB[5] = 135 + tb1.y;
    ridB[6] = 162 + tb1.z; ridB[7] = 189 + tb1.w;
    dstA = out + (long long)(b0 * T + tA) * V;
    dstB = dstA + T * V;
  } else {
    const int g = (blockIdx.x - MAIN_BLOCKS) * 256 + threadIdx.x;
    if (g >= PRE_PAIRS) return;         // after __syncthreads, safe
    const int i0 = 2 * g;
    const int i1 = (i0 + 1 < NPRE) ? i0 + 1 : i0;   // clamp: dup row, benign
    decode_prefix(i0, tA, ridA);
    decode_prefix(i1, tB, ridB);
    dstA = ws + WS_P + i0 * V;
    dstB = ws + WS_P + i1 * V;
  }

  compute_pair(tA, ridA, dstA, tB, ridB, dstB, ws, sW1T, sW2, sWoT);
}

// ---- kernel G: gather t<=2 rows; thread per (b, r), r in [0,81):
//      each b's three output rows are one contiguous 324B write run ----
__global__ __launch_bounds__(256) void gather_kernel(
    const int* __restrict__ tokens,
    const float* __restrict__ ws,
    float* __restrict__ out) {
  const int idx = blockIdx.x * 256 + threadIdx.x;   // [0, BTOT*81), exact
  const int b = idx / 81;
  const int r = idx - b * 81;
  const int t = r / 27;
  const int j = r - t * 27;
  const int t0 = tokens[b * T + 0];
  const int t1 = tokens[b * T + 1];
  const int t2 = tokens[b * T + 2];
  const int p01 = t0 * 27 + t1;
  const int pi = (t == 0) ? t0
               : (t == 1) ? (NPRE0 + p01)
                          : (NPRE0 + NPRE1 + p01 * 27 + t2);
  out[(long long)b * (T * V) + r] = ws[WS_P + pi * V + j];
}

// ---- fallback: all rows, 2 rows/thread (same b, t even/odd) ----
__global__ __launch_bounds__(256) void mini_kernel_all(
    const int* __restrict__ tokens,
    const float* __restrict__ ws,
    const float* __restrict__ W1, const float* __restrict__ W2,
    const float* __restrict__ Wo, float* __restrict__ out) {
  __shared__ h8 sW1T[H * 4];
  __shared__ h8 sW2[H * 4];
  __shared__ h8 sWoT[V * 4];
  stage_weights(W1, W2, Wo, sW1T, sW2, sWoT);

  const int gid = blockIdx.x * 256 + threadIdx.x;   // [0, BTOT*T/2)
  const int r0 = 2 * gid;                           // even => same b
  const int b = r0 >> 3;
  const int t = r0 & 7;
  const int4 ta = *(const int4*)(tokens + b * T);
  const int4 tb = *(const int4*)(tokens + b * T + 4);
  int rid[T];
  rid[0] = ta.x;       rid[1] = 27 + ta.y;
  rid[2] = 54 + ta.z;  rid[3] = 81 + ta.w;
  rid[4] = 108 + tb.x; rid[5] = 135 + tb.y;
  rid[6] = 162 + tb.z; rid[7] = 189 + tb.w;
  float* dstA = out + (long long)r0 * V;
  compute_pair(t, rid, dstA, t + 1, rid, dstA + V, ws, sW1T, sW2, sWoT);
}

extern "C" void kernel_launch(void* const* d_in, const int* in_sizes, int n_in,
                              void* d_out, int out_size, void* d_ws, size_t ws_size,
                              hipStream_t stream) {
  const int*   tokens  = (const int*)d_in[0];
  const float* tok_emb = (const float*)d_in[1];
  const float* pos_emb = (const float*)d_in[2];
  const float* Wq      = (const float*)d_in[3];
  const float* Wk      = (const float*)d_in[4];
  const float* Wv      = (const float*)d_in[5];
  const float* W1      = (const float*)d_in[6];
  const float* W2      = (const float*)d_in[7];
  const float* Wout    = (const float*)d_in[8];
  float* ws = (float*)d_ws;
  float* out = (float*)d_out;

  hipLaunchKernelGGL(build_rows_kernel, dim3((NROW * D + 255) / 256), dim3(256), 0,
                     stream, tok_emb, pos_emb, Wq, Wk, Wv, ws);
  hipLaunchKernelGGL(build_sc_kernel, dim3((NSC + 255) / 256), dim3(256), 0, stream, ws);

  if (ws_size >= WS_NEED_BIG) {
    hipLaunchKernelGGL(fused_main_kernel, dim3(MAIN_BLOCKS + PRE_BLOCKS), dim3(256), 0,
                       stream, tokens, ws, W1, W2, Wout, out);
    hipLaunchKernelGGL(gather_kernel, dim3((BTOT * 81) / 256), dim3(256), 0, stream,
                       tokens, ws, out);
  } else {
    hipLaunchKernelGGL(mini_kernel_all, dim3((BTOT * T / 2) / 256), dim3(256), 0,
                       stream, tokens, ws, W1, W2, Wout, out);
  }
}

// Round 11
// 277.747 us; speedup vs baseline: 1.0469x; 1.0083x over previous
//
#include <hip/hip_runtime.h>

// MiniTransformer: B=131072, T=8, D=32, H=64, V=27  (f32 in/out)
// R17: R14 structure + dual-pipe weights (LDS W1/Wout, global-f16 W2).
//   R15/R16 post-mortem: 2-rows/thread spills no matter the discipline
//   (VGPR 76-88 granted vs ~90-115 live; WRITE 179-219MB) => register
//   route to halving LDS traffic is dead. Reverted to R14 base.
//   Corrected model: weight reads are wave-uniform broadcasts: 620
//   ds_read_b128/WAVE x 41 waves/CU ~= 25.6k DS instr/CU x ~10-12cy
//   = 256-307k cyc ~= the 317k-cyc wall => LDS pipe saturated.
//   R17: route W2 (used with slack, after hj) through GLOBAL f16 tables
//   staged once in ws; W1 (hj critical path) + Wout stay LDS.
//   DS/wave 620->364 (-41%); +256 uniform VMEM on the idle vector pipe.
//   Single-row/thread => VGPR ~44-64, no spill risk.
//   TELLS: dur < 115us & WRITE ~108MB. dur >= 125 => LDS model wrong,
//   pivot (MFMA / latency). ws gate keeps R14 + fallback as safety nets.

namespace {
constexpr int BTOT = 131072;     // 2^17
constexpr int T = 8;
constexpr int D = 32;
constexpr int H = 64;
constexpr int V = 27;
constexpr int NTOK = 27;
constexpr int NROW = T * NTOK;   // 216
constexpr float EPS = 1e-5f;

// ws layout (float offsets)
constexpr int WS_X  = 0;             // 216*32
constexpr int WS_Q  = 6912;
constexpr int WS_K  = 13824;
constexpr int WS_V  = 20736;
constexpr int WS_SC = 27648;         // 216*216 = 46656
constexpr int NSC   = NROW * NROW;
constexpr int WS_P  = WS_SC + NSC;   // 74304: prefix-output tables
constexpr int NPRE0 = 27;
constexpr int NPRE1 = 729;
constexpr int NPRE2 = 19683;
constexpr int NPRE  = NPRE0 + NPRE1 + NPRE2;   // 20439
constexpr int WS_W16 = WS_P + NPRE * V;        // 626157: f16 weight tables
constexpr int NW16F  = (2 * H * D + V * D + 1) / 2;   // 4960 halves -> 2480 f32
constexpr size_t WS_NEED_BIG  = (size_t)WS_W16 * 4;           // ~2.50 MB
constexpr size_t WS_NEED_BIG2 = (size_t)(WS_W16 + NW16F) * 4; // +9.9 KB

constexpr int MAIN_BLOCKS = (5 * BTOT) / 256;          // 2560, exact
constexpr int PRE_BLOCKS  = (NPRE + 255) / 256;        // 80
} // namespace

typedef _Float16 h2 __attribute__((ext_vector_type(2)));
typedef _Float16 h8 __attribute__((ext_vector_type(8)));   // 16B reads

#define FMA2(a, b, c) __builtin_elementwise_fma((a), (b), (c))

// acc(4 chains) += w(8 halves) . x(4x h2)
__device__ __forceinline__ void dot8(const h8 w, const h2* x,
                                     h2& a0, h2& a1, h2& a2, h2& a3) {
  a0 = FMA2(__builtin_shufflevector(w, w, 0, 1), x[0], a0);
  a1 = FMA2(__builtin_shufflevector(w, w, 2, 3), x[1], a1);
  a2 = FMA2(__builtin_shufflevector(w, w, 4, 5), x[2], a2);
  a3 = FMA2(__builtin_shufflevector(w, w, 6, 7), x[3], a3);
}
// y(4x h2) += hb * w(8 halves)
__device__ __forceinline__ void axpy8(const h2 hb, const h8 w, h2* y) {
  y[0] = FMA2(hb, __builtin_shufflevector(w, w, 0, 1), y[0]);
  y[1] = FMA2(hb, __builtin_shufflevector(w, w, 2, 3), y[1]);
  y[2] = FMA2(hb, __builtin_shufflevector(w, w, 4, 5), y[2]);
  y[3] = FMA2(hb, __builtin_shufflevector(w, w, 6, 7), y[3]);
}

// ---- kernel A: X/Q/K/V row tables, thread per (row,d) ----
__global__ __launch_bounds__(256) void build_rows_kernel(
    const float* __restrict__ tokE, const float* __restrict__ posE,
    const float* __restrict__ Wq, const float* __restrict__ Wk,
    const float* __restrict__ Wv, float* __restrict__ ws) {
  const int idx = blockIdx.x * 256 + threadIdx.x;
  if (idx >= NROW * D) return;
  const int row = idx >> 5, d = idx & 31;
  const int t = row / NTOK, tok = row % NTOK;
  float x[D];
#pragma unroll
  for (int g = 0; g < D / 4; ++g) {
    const float4 a = *(const float4*)(tokE + tok * D + 4 * g);
    const float4 c = *(const float4*)(posE + t * D + 4 * g);
    x[4 * g + 0] = a.x + c.x;
    x[4 * g + 1] = a.y + c.y;
    x[4 * g + 2] = a.z + c.z;
    x[4 * g + 3] = a.w + c.w;
  }
  float aq = 0.f, ak = 0.f, av = 0.f;
#pragma unroll
  for (int k = 0; k < D; ++k) {
    const float xv = x[k];
    aq = fmaf(xv, Wq[k * D + d], aq);
    ak = fmaf(xv, Wk[k * D + d], ak);
    av = fmaf(xv, Wv[k * D + d], av);
  }
  ws[WS_X + row * D + d] = x[d];
  ws[WS_Q + row * D + d] = aq;
  ws[WS_K + row * D + d] = ak;
  ws[WS_V + row * D + d] = av;
}

// ---- kernel A2: stage f16 weight tables into ws (one block) ----
// layout at WS_W16 (halves): [0,2048) W1T[j*32+d], [2048,4096) W2[j*32+d],
//                            [4096,4960) WoT[v*32+d]
__global__ __launch_bounds__(256) void stage_w16_kernel(
    const float* __restrict__ W1, const float* __restrict__ W2,
    const float* __restrict__ Wo, float* __restrict__ ws) {
  _Float16* gw = (_Float16*)(ws + WS_W16);
  const int tid = threadIdx.x;
  for (int i = tid; i < H * D; i += 256) {
    const int j = i >> 5, d = i & 31;
    gw[i] = (_Float16)W1[d * H + j];
    gw[H * D + i] = (_Float16)W2[i];
  }
  for (int i = tid; i < V * D; i += 256) {
    const int v = i >> 5, d = i & 31;
    gw[2 * H * D + i] = (_Float16)Wo[d * V + v];
  }
}

// ---- kernel B: score table SC[(t*27+tokt)*216 + s*27+toks] ----
__global__ __launch_bounds__(256) void build_sc_kernel(float* __restrict__ ws) {
  const int i = blockIdx.x * 256 + threadIdx.x;
  if (i >= NSC) return;
  const int qrow = i / NROW;
  const int j    = i - qrow * NROW;
  const float4* q = (const float4*)(ws + WS_Q + qrow * D);
  const float4* k = (const float4*)(ws + WS_K + j * D);
  float a = 0.f;
#pragma unroll
  for (int g = 0; g < D / 4; ++g) {
    const float4 qa = q[g], ka = k[g];
    a = fmaf(qa.x, ka.x, a);
    a = fmaf(qa.y, ka.y, a);
    a = fmaf(qa.z, ka.z, a);
    a = fmaf(qa.w, ka.w, a);
  }
  ws[WS_SC + i] = a;
}

// ---- row computation: f32 attention/LN stats, f16 MLP+Wout ----
// w1src/w2src/wosrc are generic pointers; each kernel's inline site
// specializes them to ds_read (LDS) or global_load (ws tables).
__device__ __forceinline__ void compute_row(
    const int t, const int* rowid,
    const float* __restrict__ ws,
    const h8* w1src, const h8* w2src, const h8* wosrc,
    float* __restrict__ dst) {
  const int qrow = rowid[t];
  const float* SC = ws + WS_SC + qrow * NROW;
  float sc[T];
#pragma unroll
  for (int s = 0; s < T; ++s)
    sc[s] = (s <= t) ? SC[rowid[s]] : -INFINITY;

  const float m01 = fmaxf(sc[0], sc[1]), m23 = fmaxf(sc[2], sc[3]);
  const float m45 = fmaxf(sc[4], sc[5]), m67 = fmaxf(sc[6], sc[7]);
  const float mx = fmaxf(fmaxf(m01, m23), fmaxf(m45, m67));

  // attention (f32): o = sum p_s * V[row_s], exp fused into loop
  float o[D];
#pragma unroll
  for (int d = 0; d < D; ++d) o[d] = 0.f;
  float den = 0.f;
#pragma unroll
  for (int s = 0; s < T; ++s) {
    if (s <= t) {
      const float ps = __expf(sc[s] - mx);
      den += ps;
      const float4* vr = (const float4*)(ws + WS_V + rowid[s] * D);
#pragma unroll
      for (int g = 0; g < D / 4; ++g) {
        const float4 v4 = vr[g];
        o[4 * g + 0] = fmaf(ps, v4.x, o[4 * g + 0]);
        o[4 * g + 1] = fmaf(ps, v4.y, o[4 * g + 1]);
        o[4 * g + 2] = fmaf(ps, v4.z, o[4 * g + 2]);
        o[4 * g + 3] = fmaf(ps, v4.w, o[4 * g + 3]);
      }
    }
  }
  const float inv = 1.f / den;
  {
    const float4* xr = (const float4*)(ws + WS_X + qrow * D);
#pragma unroll
    for (int g = 0; g < D / 4; ++g) {
      const float4 x4 = xr[g];
      o[4 * g + 0] = fmaf(o[4 * g + 0], inv, x4.x);
      o[4 * g + 1] = fmaf(o[4 * g + 1], inv, x4.y);
      o[4 * g + 2] = fmaf(o[4 * g + 2], inv, x4.z);
      o[4 * g + 3] = fmaf(o[4 * g + 3], inv, x4.w);
    }
  }

  // LayerNorm 1 (f32 stats), normalize fused into the f16 pack
  h2 o2[16];
  {
    float s1a = 0.f, s1b = 0.f, s1c = 0.f, s1d = 0.f;
#pragma unroll
    for (int d = 0; d < D; d += 4) {
      s1a += o[d]; s1b += o[d + 1]; s1c += o[d + 2]; s1d += o[d + 3];
    }
    const float mean = ((s1a + s1b) + (s1c + s1d)) * (1.f / D);
    float q0 = 0.f, q1 = 0.f, q2 = 0.f, q3 = 0.f;
#pragma unroll
    for (int d = 0; d < D; d += 4) {
      const float c0 = o[d] - mean, c1 = o[d + 1] - mean;
      const float c2 = o[d + 2] - mean, c3 = o[d + 3] - mean;
      q0 = fmaf(c0, c0, q0); q1 = fmaf(c1, c1, q1);
      q2 = fmaf(c2, c2, q2); q3 = fmaf(c3, c3, q3);
    }
    const float rr = rsqrtf(((q0 + q1) + (q2 + q3)) * (1.f / D) + EPS);
#pragma unroll
    for (int k = 0; k < 16; ++k) {
      o2[k] = h2{(_Float16)((o[2 * k] - mean) * rr),
                 (_Float16)((o[2 * k + 1] - mean) * rr)};
    }
  }

  // MLP: W2 quads loaded FIRST (global path has hj-latency of slack),
  // W1 quads (LDS, low latency) feed the hj critical path.
  h2 y2[16];
#pragma unroll
  for (int k = 0; k < 16; ++k) y2[k] = o2[k];   // residual pre-add
#pragma unroll
  for (int j = 0; j < H; ++j) {
    const h8 u0 = w2src[j * 4 + 0], u1 = w2src[j * 4 + 1];
    const h8 u2 = w2src[j * 4 + 2], u3 = w2src[j * 4 + 3];
    const h8 wa = w1src[j * 4 + 0], wb = w1src[j * 4 + 1];
    const h8 wc = w1src[j * 4 + 2], wd = w1src[j * 4 + 3];
    h2 a0 = h2{(_Float16)0.f, (_Float16)0.f};
    h2 a1 = a0, a2 = a0, a3 = a0;
    dot8(wa, &o2[0], a0, a1, a2, a3);
    dot8(wb, &o2[4], a0, a1, a2, a3);
    dot8(wc, &o2[8], a0, a1, a2, a3);
    dot8(wd, &o2[12], a0, a1, a2, a3);
    const h2 hs = (a0 + a1) + (a2 + a3);
    _Float16 hj = (_Float16)(hs[0] + hs[1]);
    hj = (hj > (_Float16)0.f) ? hj : (_Float16)0.f;
    const h2 hb = h2{hj, hj};
    axpy8(hb, u0, &y2[0]);
    axpy8(hb, u1, &y2[4]);
    axpy8(hb, u2, &y2[8]);
    axpy8(hb, u3, &y2[12]);
  }

  // LayerNorm 2 (f32 stats, f16 repack)
  {
    float z[D];
#pragma unroll
    for (int k = 0; k < 16; ++k) {
      z[2 * k]     = (float)y2[k][0];
      z[2 * k + 1] = (float)y2[k][1];
    }
    float s1a = 0.f, s1b = 0.f, s1c = 0.f, s1d = 0.f;
#pragma unroll
    for (int d = 0; d < D; d += 4) {
      s1a += z[d]; s1b += z[d + 1]; s1c += z[d + 2]; s1d += z[d + 3];
    }
    const float mean = ((s1a + s1b) + (s1c + s1d)) * (1.f / D);
    float q0 = 0.f, q1 = 0.f, q2 = 0.f, q3 = 0.f;
#pragma unroll
    for (int d = 0; d < D; d += 4) {
      const float c0 = z[d] - mean, c1 = z[d + 1] - mean;
      const float c2 = z[d + 2] - mean, c3 = z[d + 3] - mean;
      q0 = fmaf(c0, c0, q0); q1 = fmaf(c1, c1, q1);
      q2 = fmaf(c2, c2, q2); q3 = fmaf(c3, c3, q3);
    }
    const float rr = rsqrtf(((q0 + q1) + (q2 + q3)) * (1.f / D) + EPS);
#pragma unroll
    for (int k = 0; k < 16; ++k) {
      y2[k] = h2{(_Float16)((z[2 * k] - mean) * rr),
                 (_Float16)((z[2 * k + 1] - mean) * rr)};
    }
  }

  // output projection (f16 packed dot per v, f32 store)
#pragma unroll
  for (int v = 0; v < V; ++v) {
    const h8 wa = wosrc[v * 4 + 0], wb = wosrc[v * 4 + 1];
    const h8 wc = wosrc[v * 4 + 2], wd = wosrc[v * 4 + 3];
    h2 a0 = h2{(_Float16)0.f, (_Float16)0.f};
    h2 a1 = a0, a2 = a0, a3 = a0;
    dot8(wa, &y2[0], a0, a1, a2, a3);
    dot8(wb, &y2[4], a0, a1, a2, a3);
    dot8(wc, &y2[8], a0, a1, a2, a3);
    dot8(wd, &y2[12], a0, a1, a2, a3);
    const h2 s = (a0 + a1) + (a2 + a3);
    dst[v] = (float)(s[0] + s[1]);
  }
}

// ---- LDS staging (full set, for the pure-LDS kernel) ----
__device__ __forceinline__ void stage_weights_all(
    const float* __restrict__ W1, const float* __restrict__ W2,
    const float* __restrict__ Wo,
    h8* sW1T, h8* sW2, h8* sWoT) {
  _Float16* a = (_Float16*)sW1T;
  _Float16* b = (_Float16*)sW2;
  _Float16* c = (_Float16*)sWoT;
  const int tid = threadIdx.x;
  for (int i = tid; i < H * D; i += 256) {
    const int j = i >> 5, d = i & 31;
    a[i] = (_Float16)W1[d * H + j];
    b[i] = (_Float16)W2[i];
  }
  for (int i = tid; i < V * D; i += 256) {
    const int v = i >> 5, d = i & 31;
    c[i] = (_Float16)Wo[d * V + v];
  }
  __syncthreads();
}

// ---- LDS staging (W1T + WoT only, for the dual kernel) ----
__device__ __forceinline__ void stage_weights_w1wo(
    const float* __restrict__ W1, const float* __restrict__ Wo,
    h8* sW1T, h8* sWoT) {
  _Float16* a = (_Float16*)sW1T;
  _Float16* c = (_Float16*)sWoT;
  const int tid = threadIdx.x;
  for (int i = tid; i < H * D; i += 256) {
    const int j = i >> 5, d = i & 31;
    a[i] = (_Float16)W1[d * H + j];
  }
  for (int i = tid; i < V * D; i += 256) {
    const int v = i >> 5, d = i & 31;
    c[i] = (_Float16)Wo[d * V + v];
  }
  __syncthreads();
}

// ---- prefix decode: i -> (t, rowid[8]) ----
__device__ __forceinline__ void decode_prefix(const int i, int& t, int* rowid) {
  int p;
  int t0 = 0, t1 = 0, t2 = 0;
  if (i < NPRE0)              { t = 0; p = i; t0 = p; }
  else if (i < NPRE0 + NPRE1) { t = 1; p = i - NPRE0; t0 = p / 27; t1 = p % 27; }
  else { t = 2; p = i - NPRE0 - NPRE1; t0 = p / 729;
         const int r = p % 729; t1 = r / 27; t2 = r % 27; }
  rowid[0] = t0; rowid[1] = 27 + t1; rowid[2] = 54 + t2;
  rowid[3] = 81; rowid[4] = 108; rowid[5] = 135; rowid[6] = 162; rowid[7] = 189;
}

// ---- kernel C (dual): t in [3,8) + prefix build; W2 from global ws ----
__global__ __launch_bounds__(256) void fused_main_dual_kernel(
    const int* __restrict__ tokens,
    float* __restrict__ ws,
    const float* __restrict__ W1, const float* __restrict__ Wo,
    float* __restrict__ out) {
  __shared__ h8 sW1T[H * 4];   // 4 KB
  __shared__ h8 sWoT[V * 4];   // 1.7 KB
  stage_weights_w1wo(W1, Wo, sW1T, sWoT);
  const h8* gW2 = (const h8*)((const _Float16*)(ws + WS_W16) + H * D);

  if (blockIdx.x < MAIN_BLOCKS) {
    const int idx = blockIdx.x * 256 + threadIdx.x;   // [0, 5*BTOT), exact
    const int t = 3 + (idx >> 17);                    // wave-uniform
    const int b = idx & (BTOT - 1);
    const int4 ta = *(const int4*)(tokens + b * T);
    const int4 tb = *(const int4*)(tokens + b * T + 4);
    int rowid[T];
    rowid[0] = ta.x;       rowid[1] = 27 + ta.y;
    rowid[2] = 54 + ta.z;  rowid[3] = 81 + ta.w;
    rowid[4] = 108 + tb.x; rowid[5] = 135 + tb.y;
    rowid[6] = 162 + tb.z; rowid[7] = 189 + tb.w;
    compute_row(t, rowid, ws, sW1T, gW2, sWoT,
                out + (long long)(b * T + t) * V);
  } else {
    const int i = (blockIdx.x - MAIN_BLOCKS) * 256 + threadIdx.x;
    if (i >= NPRE) return;
    int t;
    int rowid[T];
    decode_prefix(i, t, rowid);
    compute_row(t, rowid, ws, sW1T, gW2, sWoT, ws + WS_P + i * V);
  }
}

// ---- kernel C (pure LDS = R14): safety net when ws lacks table room ----
__global__ __launch_bounds__(256) void fused_main_lds_kernel(
    const int* __restrict__ tokens,
    float* __restrict__ ws,
    const float* __restrict__ W1, const float* __restrict__ W2,
    const float* __restrict__ Wo, float* __restrict__ out) {
  __shared__ h8 sW1T[H * 4];
  __shared__ h8 sW2[H * 4];
  __shared__ h8 sWoT[V * 4];
  stage_weights_all(W1, W2, Wo, sW1T, sW2, sWoT);

  if (blockIdx.x < MAIN_BLOCKS) {
    const int idx = blockIdx.x * 256 + threadIdx.x;
    const int t = 3 + (idx >> 17);
    const int b = idx & (BTOT - 1);
    const int4 ta = *(const int4*)(tokens + b * T);
    const int4 tb = *(const int4*)(tokens + b * T + 4);
    int rowid[T];
    rowid[0] = ta.x;       rowid[1] = 27 + ta.y;
    rowid[2] = 54 + ta.z;  rowid[3] = 81 + ta.w;
    rowid[4] = 108 + tb.x; rowid[5] = 135 + tb.y;
    rowid[6] = 162 + tb.z; rowid[7] = 189 + tb.w;
    compute_row(t, rowid, ws, sW1T, sW2, sWoT,
                out + (long long)(b * T + t) * V);
  } else {
    const int i = (blockIdx.x - MAIN_BLOCKS) * 256 + threadIdx.x;
    if (i >= NPRE) return;
    int t;
    int rowid[T];
    decode_prefix(i, t, rowid);
    compute_row(t, rowid, ws, sW1T, sW2, sWoT, ws + WS_P + i * V);
  }
}

// ---- kernel G: gather t<=2 rows; thread per (b, r), r in [0,81) ----
__global__ __launch_bounds__(256) void gather_kernel(
    const int* __restrict__ tokens,
    const float* __restrict__ ws,
    float* __restrict__ out) {
  const int idx = blockIdx.x * 256 + threadIdx.x;   // [0, BTOT*81), exact
  const int b = idx / 81;
  const int r = idx - b * 81;
  const int t = r / 27;
  const int j = r - t * 27;
  const int t0 = tokens[b * T + 0];
  const int t1 = tokens[b * T + 1];
  const int t2 = tokens[b * T + 2];
  const int p01 = t0 * 27 + t1;
  const int pi = (t == 0) ? t0
               : (t == 1) ? (NPRE0 + p01)
                          : (NPRE0 + NPRE1 + p01 * 27 + t2);
  out[(long long)b * (T * V) + r] = ws[WS_P + pi * V + j];
}

// ---- fallback: all rows, thread per row ----
__global__ __launch_bounds__(256) void mini_kernel_all(
    const int* __restrict__ tokens,
    const float* __restrict__ ws,
    const float* __restrict__ W1, const float* __restrict__ W2,
    const float* __restrict__ Wo, float* __restrict__ out) {
  __shared__ h8 sW1T[H * 4];
  __shared__ h8 sW2[H * 4];
  __shared__ h8 sWoT[V * 4];
  stage_weights_all(W1, W2, Wo, sW1T, sW2, sWoT);

  const int r = blockIdx.x * 256 + threadIdx.x;
  const int b = r >> 3;
  const int t = r & 7;
  const int4 ta = *(const int4*)(tokens + b * T);
  const int4 tb = *(const int4*)(tokens + b * T + 4);
  int rowid[T];
  rowid[0] = ta.x;       rowid[1] = 27 + ta.y;
  rowid[2] = 54 + ta.z;  rowid[3] = 81 + ta.w;
  rowid[4] = 108 + tb.x; rowid[5] = 135 + tb.y;
  rowid[6] = 162 + tb.z; rowid[7] = 189 + tb.w;
  compute_row(t, rowid, ws, sW1T, sW2, sWoT, out + (long long)r * V);
}

extern "C" void kernel_launch(void* const* d_in, const int* in_sizes, int n_in,
                              void* d_out, int out_size, void* d_ws, size_t ws_size,
                              hipStream_t stream) {
  const int*   tokens  = (const int*)d_in[0];
  const float* tok_emb = (const float*)d_in[1];
  const float* pos_emb = (const float*)d_in[2];
  const float* Wq      = (const float*)d_in[3];
  const float* Wk      = (const float*)d_in[4];
  const float* Wv      = (const float*)d_in[5];
  const float* W1      = (const float*)d_in[6];
  const float* W2      = (const float*)d_in[7];
  const float* Wout    = (const float*)d_in[8];
  float* ws = (float*)d_ws;
  float* out = (float*)d_out;

  hipLaunchKernelGGL(build_rows_kernel, dim3((NROW * D + 255) / 256), dim3(256), 0,
                     stream, tok_emb, pos_emb, Wq, Wk, Wv, ws);
  hipLaunchKernelGGL(build_sc_kernel, dim3((NSC + 255) / 256), dim3(256), 0, stream, ws);

  if (ws_size >= WS_NEED_BIG2) {
    hipLaunchKernelGGL(stage_w16_kernel, dim3(1), dim3(256), 0, stream,
                       W1, W2, Wout, ws);
    hipLaunchKernelGGL(fused_main_dual_kernel, dim3(MAIN_BLOCKS + PRE_BLOCKS),
                       dim3(256), 0, stream, tokens, ws, W1, Wout, out);
    hipLaunchKernelGGL(gather_kernel, dim3((BTOT * 81) / 256), dim3(256), 0, stream,
                       tokens, ws, out);
  } else if (ws_size >= WS_NEED_BIG) {
    hipLaunchKernelGGL(fused_main_lds_kernel, dim3(MAIN_BLOCKS + PRE_BLOCKS),
                       dim3(256), 0, stream, tokens, ws, W1, W2, Wout, out);
    hipLaunchKernelGGL(gather_kernel, dim3((BTOT * 81) / 256), dim3(256), 0, stream,
                       tokens, ws, out);
  } else {
    hipLaunchKernelGGL(mini_kernel_all, dim3((BTOT * T) / 256), dim3(256), 0,
                       stream, tokens, ws, W1, W2, Wout, out);
  }
}

// Round 12
// 237.277 us; speedup vs baseline: 1.2254x; 1.1706x over previous
//
#include <hip/hip_runtime.h>

// MiniTransformer: B=131072, T=8, D=32, H=64, V=27  (f32 in/out)
// R18: R14 (best, 132us) + f16 V/X gather tables (attention latency fix).
//   R17 post-mortem: DS 620->364 made it SLOWER (142us) => LDS-pipe-
//   saturation model refuted; W2 reverted to LDS. Remaining ~160k cyc of
//   stall attributed to the attention gathers: ~68 lane-divergent VMEM/row
//   into 55KB f32 V/X (doesn't fit 32KB L1 => ~200cy L2) + 186KB SC.
//   Fix: build_rows also writes V,X as f16 rows (64B = 1 line/row):
//   VMEM/row 52->24, footprint 27.6KB fits L1, in-flight bytes halve.
//   o-accumulate via fmaf(ps,(float)v16,o) => v_fma_mix_f32 (f32 acc).
//   SC stays f32. MLP/LN identical to R14. 3-tier ws gate keeps R14 path
//   + mini fallback.
//   TELL: dur < 120us validates the gather-latency model; <5% delta =>
//   attention VMEM not the wall -> pivot (occupancy / MFMA).

namespace {
constexpr int BTOT = 131072;     // 2^17
constexpr int T = 8;
constexpr int D = 32;
constexpr int H = 64;
constexpr int V = 27;
constexpr int NTOK = 27;
constexpr int NROW = T * NTOK;   // 216
constexpr float EPS = 1e-5f;

// ws layout (float offsets)
constexpr int WS_X  = 0;             // 216*32
constexpr int WS_Q  = 6912;
constexpr int WS_K  = 13824;
constexpr int WS_V  = 20736;
constexpr int WS_SC = 27648;         // 216*216 = 46656
constexpr int NSC   = NROW * NROW;
constexpr int WS_P  = WS_SC + NSC;   // 74304: prefix-output tables
constexpr int NPRE0 = 27;
constexpr int NPRE1 = 729;
constexpr int NPRE2 = 19683;
constexpr int NPRE  = NPRE0 + NPRE1 + NPRE2;   // 20439
constexpr size_t WS_NEED_BIG = (size_t)(WS_P + NPRE * V) * 4;  // ~2.50 MB

// f16 V/X tables (16B-aligned float offset)
constexpr int WS_V16F = ((WS_P + NPRE * V) + 3) & ~3;   // 626160
constexpr int WS_X16F = WS_V16F + (NROW * D) / 2;       // +3456
constexpr size_t WS_NEED_F16 = (size_t)(WS_X16F + (NROW * D) / 2) * 4;

constexpr int MAIN_BLOCKS = (5 * BTOT) / 256;          // 2560, exact
constexpr int PRE_BLOCKS  = (NPRE + 255) / 256;        // 80
} // namespace

typedef _Float16 h2 __attribute__((ext_vector_type(2)));
typedef _Float16 h8 __attribute__((ext_vector_type(8)));   // 16B reads

#define FMA2(a, b, c) __builtin_elementwise_fma((a), (b), (c))

// acc(4 chains) += w(8 halves) . x(4x h2)
__device__ __forceinline__ void dot8(const h8 w, const h2* x,
                                     h2& a0, h2& a1, h2& a2, h2& a3) {
  a0 = FMA2(__builtin_shufflevector(w, w, 0, 1), x[0], a0);
  a1 = FMA2(__builtin_shufflevector(w, w, 2, 3), x[1], a1);
  a2 = FMA2(__builtin_shufflevector(w, w, 4, 5), x[2], a2);
  a3 = FMA2(__builtin_shufflevector(w, w, 6, 7), x[3], a3);
}
// y(4x h2) += hb * w(8 halves)
__device__ __forceinline__ void axpy8(const h2 hb, const h8 w, h2* y) {
  y[0] = FMA2(hb, __builtin_shufflevector(w, w, 0, 1), y[0]);
  y[1] = FMA2(hb, __builtin_shufflevector(w, w, 2, 3), y[1]);
  y[2] = FMA2(hb, __builtin_shufflevector(w, w, 4, 5), y[2]);
  y[3] = FMA2(hb, __builtin_shufflevector(w, w, 6, 7), y[3]);
}

// ---- kernel A: X/Q/K/V row tables (+ optional f16 V/X copies) ----
__global__ __launch_bounds__(256) void build_rows_kernel(
    const float* __restrict__ tokE, const float* __restrict__ posE,
    const float* __restrict__ Wq, const float* __restrict__ Wk,
    const float* __restrict__ Wv, float* __restrict__ ws, const int wf16) {
  const int idx = blockIdx.x * 256 + threadIdx.x;
  if (idx >= NROW * D) return;
  const int row = idx >> 5, d = idx & 31;
  const int t = row / NTOK, tok = row % NTOK;
  float x[D];
#pragma unroll
  for (int g = 0; g < D / 4; ++g) {
    const float4 a = *(const float4*)(tokE + tok * D + 4 * g);
    const float4 c = *(const float4*)(posE + t * D + 4 * g);
    x[4 * g + 0] = a.x + c.x;
    x[4 * g + 1] = a.y + c.y;
    x[4 * g + 2] = a.z + c.z;
    x[4 * g + 3] = a.w + c.w;
  }
  float aq = 0.f, ak = 0.f, av = 0.f;
#pragma unroll
  for (int k = 0; k < D; ++k) {
    const float xv = x[k];
    aq = fmaf(xv, Wq[k * D + d], aq);
    ak = fmaf(xv, Wk[k * D + d], ak);
    av = fmaf(xv, Wv[k * D + d], av);
  }
  ws[WS_X + row * D + d] = x[d];
  ws[WS_Q + row * D + d] = aq;
  ws[WS_K + row * D + d] = ak;
  ws[WS_V + row * D + d] = av;
  if (wf16) {
    _Float16* v16 = (_Float16*)(ws + WS_V16F);
    _Float16* x16 = (_Float16*)(ws + WS_X16F);
    v16[row * D + d] = (_Float16)av;
    x16[row * D + d] = (_Float16)x[d];
  }
}

// ---- kernel B: score table SC[(t*27+tokt)*216 + s*27+toks] ----
__global__ __launch_bounds__(256) void build_sc_kernel(float* __restrict__ ws) {
  const int i = blockIdx.x * 256 + threadIdx.x;
  if (i >= NSC) return;
  const int qrow = i / NROW;
  const int j    = i - qrow * NROW;
  const float4* q = (const float4*)(ws + WS_Q + qrow * D);
  const float4* k = (const float4*)(ws + WS_K + j * D);
  float a = 0.f;
#pragma unroll
  for (int g = 0; g < D / 4; ++g) {
    const float4 qa = q[g], ka = k[g];
    a = fmaf(qa.x, ka.x, a);
    a = fmaf(qa.y, ka.y, a);
    a = fmaf(qa.z, ka.z, a);
    a = fmaf(qa.w, ka.w, a);
  }
  ws[WS_SC + i] = a;
}

// ---- shared MLP + LN2 + Wout tail (f16 packed, weights from LDS) ----
__device__ __forceinline__ void mlp_tail(
    h2* o2, const h8* sW1T, const h8* sW2, const h8* sWoT,
    float* __restrict__ dst) {
  h2 y2[16];
#pragma unroll
  for (int k = 0; k < 16; ++k) y2[k] = h2{(_Float16)0.f, (_Float16)0.f};
#pragma unroll
  for (int j = 0; j < H; ++j) {
    const h8 wa = sW1T[j * 4 + 0], wb = sW1T[j * 4 + 1];
    const h8 wc = sW1T[j * 4 + 2], wd = sW1T[j * 4 + 3];
    h2 a0 = h2{(_Float16)0.f, (_Float16)0.f};
    h2 a1 = a0, a2 = a0, a3 = a0;
    dot8(wa, &o2[0], a0, a1, a2, a3);
    dot8(wb, &o2[4], a0, a1, a2, a3);
    dot8(wc, &o2[8], a0, a1, a2, a3);
    dot8(wd, &o2[12], a0, a1, a2, a3);
    const h2 hs = (a0 + a1) + (a2 + a3);
    _Float16 hj = (_Float16)(hs[0] + hs[1]);
    hj = (hj > (_Float16)0.f) ? hj : (_Float16)0.f;
    const h2 hb = h2{hj, hj};
    const h8 va = sW2[j * 4 + 0], vb = sW2[j * 4 + 1];
    const h8 vc = sW2[j * 4 + 2], vd = sW2[j * 4 + 3];
    axpy8(hb, va, &y2[0]);
    axpy8(hb, vb, &y2[4]);
    axpy8(hb, vc, &y2[8]);
    axpy8(hb, vd, &y2[12]);
  }

  // residual + LayerNorm 2 (f32 stats, f16 repack)
#pragma unroll
  for (int k = 0; k < 16; ++k) y2[k] = y2[k] + o2[k];
  {
    float z[D];
#pragma unroll
    for (int k = 0; k < 16; ++k) {
      z[2 * k]     = (float)y2[k][0];
      z[2 * k + 1] = (float)y2[k][1];
    }
    float s1a = 0.f, s1b = 0.f, s1c = 0.f, s1d = 0.f;
#pragma unroll
    for (int d = 0; d < D; d += 4) {
      s1a += z[d]; s1b += z[d + 1]; s1c += z[d + 2]; s1d += z[d + 3];
    }
    const float mean = ((s1a + s1b) + (s1c + s1d)) * (1.f / D);
    float q0 = 0.f, q1 = 0.f, q2 = 0.f, q3 = 0.f;
#pragma unroll
    for (int d = 0; d < D; d += 4) {
      const float c0 = z[d] - mean, c1 = z[d + 1] - mean;
      const float c2 = z[d + 2] - mean, c3 = z[d + 3] - mean;
      q0 = fmaf(c0, c0, q0); q1 = fmaf(c1, c1, q1);
      q2 = fmaf(c2, c2, q2); q3 = fmaf(c3, c3, q3);
    }
    const float rr = rsqrtf(((q0 + q1) + (q2 + q3)) * (1.f / D) + EPS);
#pragma unroll
    for (int k = 0; k < 16; ++k) {
      y2[k] = h2{(_Float16)((z[2 * k] - mean) * rr),
                 (_Float16)((z[2 * k + 1] - mean) * rr)};
    }
  }

  // output projection (f16 packed dot per v, f32 store)
#pragma unroll
  for (int v = 0; v < V; ++v) {
    const h8 wa = sWoT[v * 4 + 0], wb = sWoT[v * 4 + 1];
    const h8 wc = sWoT[v * 4 + 2], wd = sWoT[v * 4 + 3];
    h2 a0 = h2{(_Float16)0.f, (_Float16)0.f};
    h2 a1 = a0, a2 = a0, a3 = a0;
    dot8(wa, &y2[0], a0, a1, a2, a3);
    dot8(wb, &y2[4], a0, a1, a2, a3);
    dot8(wc, &y2[8], a0, a1, a2, a3);
    dot8(wd, &y2[12], a0, a1, a2, a3);
    const h2 s = (a0 + a1) + (a2 + a3);
    dst[v] = (float)(s[0] + s[1]);
  }
}

// ---- attention + LN1, f16 V/X tables (v_fma_mix accumulate) ----
__device__ __forceinline__ void attn_ln1_f16(
    const int t, const int* rowid, const float* __restrict__ ws, h2* o2) {
  const int qrow = rowid[t];
  const float* SC = ws + WS_SC + qrow * NROW;
  const h8* v16 = (const h8*)(ws + WS_V16F);
  const h8* x16 = (const h8*)(ws + WS_X16F);
  float sc[T];
#pragma unroll
  for (int s = 0; s < T; ++s)
    sc[s] = (s <= t) ? SC[rowid[s]] : -INFINITY;

  const float m01 = fmaxf(sc[0], sc[1]), m23 = fmaxf(sc[2], sc[3]);
  const float m45 = fmaxf(sc[4], sc[5]), m67 = fmaxf(sc[6], sc[7]);
  const float mx = fmaxf(fmaxf(m01, m23), fmaxf(m45, m67));

  float o[D];
#pragma unroll
  for (int d = 0; d < D; ++d) o[d] = 0.f;
  float den = 0.f;
#pragma unroll
  for (int s = 0; s < T; ++s) {
    if (s <= t) {
      const float ps = __expf(sc[s] - mx);
      den += ps;
      const h8* vr = v16 + rowid[s] * 4;     // 4x 16B = one 64B line
#pragma unroll
      for (int g = 0; g < 4; ++g) {
        const h8 v8 = vr[g];
#pragma unroll
        for (int kk = 0; kk < 8; ++kk)
          o[8 * g + kk] = fmaf(ps, (float)v8[kk], o[8 * g + kk]);
      }
    }
  }
  const float inv = 1.f / den;
  {
    const h8* xr = x16 + qrow * 4;
#pragma unroll
    for (int g = 0; g < 4; ++g) {
      const h8 x8 = xr[g];
#pragma unroll
      for (int kk = 0; kk < 8; ++kk)
        o[8 * g + kk] = fmaf(o[8 * g + kk], inv, (float)x8[kk]);
    }
  }

  float s1a = 0.f, s1b = 0.f, s1c = 0.f, s1d = 0.f;
#pragma unroll
  for (int d = 0; d < D; d += 4) {
    s1a += o[d]; s1b += o[d + 1]; s1c += o[d + 2]; s1d += o[d + 3];
  }
  const float mean = ((s1a + s1b) + (s1c + s1d)) * (1.f / D);
  float q0 = 0.f, q1 = 0.f, q2 = 0.f, q3 = 0.f;
#pragma unroll
  for (int d = 0; d < D; d += 4) {
    const float c0 = o[d] - mean, c1 = o[d + 1] - mean;
    const float c2 = o[d + 2] - mean, c3 = o[d + 3] - mean;
    q0 = fmaf(c0, c0, q0); q1 = fmaf(c1, c1, q1);
    q2 = fmaf(c2, c2, q2); q3 = fmaf(c3, c3, q3);
  }
  const float rr = rsqrtf(((q0 + q1) + (q2 + q3)) * (1.f / D) + EPS);
#pragma unroll
  for (int k = 0; k < 16; ++k) {
    o2[k] = h2{(_Float16)((o[2 * k] - mean) * rr),
               (_Float16)((o[2 * k + 1] - mean) * rr)};
  }
}

// ---- attention + LN1, f32 V/X tables (R14 path) ----
__device__ __forceinline__ void attn_ln1_f32(
    const int t, const int* rowid, const float* __restrict__ ws, h2* o2) {
  const int qrow = rowid[t];
  const float* SC = ws + WS_SC + qrow * NROW;
  float sc[T];
#pragma unroll
  for (int s = 0; s < T; ++s)
    sc[s] = (s <= t) ? SC[rowid[s]] : -INFINITY;

  const float m01 = fmaxf(sc[0], sc[1]), m23 = fmaxf(sc[2], sc[3]);
  const float m45 = fmaxf(sc[4], sc[5]), m67 = fmaxf(sc[6], sc[7]);
  const float mx = fmaxf(fmaxf(m01, m23), fmaxf(m45, m67));

  float o[D];
#pragma unroll
  for (int d = 0; d < D; ++d) o[d] = 0.f;
  float den = 0.f;
#pragma unroll
  for (int s = 0; s < T; ++s) {
    if (s <= t) {
      const float ps = __expf(sc[s] - mx);
      den += ps;
      const float4* vr = (const float4*)(ws + WS_V + rowid[s] * D);
#pragma unroll
      for (int g = 0; g < D / 4; ++g) {
        const float4 v4 = vr[g];
        o[4 * g + 0] = fmaf(ps, v4.x, o[4 * g + 0]);
        o[4 * g + 1] = fmaf(ps, v4.y, o[4 * g + 1]);
        o[4 * g + 2] = fmaf(ps, v4.z, o[4 * g + 2]);
        o[4 * g + 3] = fmaf(ps, v4.w, o[4 * g + 3]);
      }
    }
  }
  const float inv = 1.f / den;
  {
    const float4* xr = (const float4*)(ws + WS_X + qrow * D);
#pragma unroll
    for (int g = 0; g < D / 4; ++g) {
      const float4 x4 = xr[g];
      o[4 * g + 0] = fmaf(o[4 * g + 0], inv, x4.x);
      o[4 * g + 1] = fmaf(o[4 * g + 1], inv, x4.y);
      o[4 * g + 2] = fmaf(o[4 * g + 2], inv, x4.z);
      o[4 * g + 3] = fmaf(o[4 * g + 3], inv, x4.w);
    }
  }

  float s1a = 0.f, s1b = 0.f, s1c = 0.f, s1d = 0.f;
#pragma unroll
  for (int d = 0; d < D; d += 4) {
    s1a += o[d]; s1b += o[d + 1]; s1c += o[d + 2]; s1d += o[d + 3];
  }
  const float mean = ((s1a + s1b) + (s1c + s1d)) * (1.f / D);
  float q0 = 0.f, q1 = 0.f, q2 = 0.f, q3 = 0.f;
#pragma unroll
  for (int d = 0; d < D; d += 4) {
    const float c0 = o[d] - mean, c1 = o[d + 1] - mean;
    const float c2 = o[d + 2] - mean, c3 = o[d + 3] - mean;
    q0 = fmaf(c0, c0, q0); q1 = fmaf(c1, c1, q1);
    q2 = fmaf(c2, c2, q2); q3 = fmaf(c3, c3, q3);
  }
  const float rr = rsqrtf(((q0 + q1) + (q2 + q3)) * (1.f / D) + EPS);
#pragma unroll
  for (int k = 0; k < 16; ++k) {
    o2[k] = h2{(_Float16)((o[2 * k] - mean) * rr),
               (_Float16)((o[2 * k + 1] - mean) * rr)};
  }
}

// ---- weight staging into LDS as f16 (W1, Wout transposed) ----
__device__ __forceinline__ void stage_weights(
    const float* __restrict__ W1, const float* __restrict__ W2,
    const float* __restrict__ Wo,
    h8* sW1T, h8* sW2, h8* sWoT) {
  _Float16* a = (_Float16*)sW1T;
  _Float16* b = (_Float16*)sW2;
  _Float16* c = (_Float16*)sWoT;
  const int tid = threadIdx.x;
  for (int i = tid; i < H * D; i += 256) {
    const int j = i >> 5, d = i & 31;           // i = j*32 + d
    a[i] = (_Float16)W1[d * H + j];             // W1T[j][d]
    b[i] = (_Float16)W2[i];                     // W2[j][d] (identity layout)
  }
  for (int i = tid; i < V * D; i += 256) {
    const int v = i >> 5, d = i & 31;           // i = v*32 + d
    c[i] = (_Float16)Wo[d * V + v];             // WoT[v][d]
  }
  __syncthreads();
}

// ---- prefix decode: i -> (t, rowid[8]) ----
__device__ __forceinline__ void decode_prefix(const int i, int& t, int* rowid) {
  int p;
  int t0 = 0, t1 = 0, t2 = 0;
  if (i < NPRE0)              { t = 0; p = i; t0 = p; }
  else if (i < NPRE0 + NPRE1) { t = 1; p = i - NPRE0; t0 = p / 27; t1 = p % 27; }
  else { t = 2; p = i - NPRE0 - NPRE1; t0 = p / 729;
         const int r = p % 729; t1 = r / 27; t2 = r % 27; }
  rowid[0] = t0; rowid[1] = 27 + t1; rowid[2] = 54 + t2;
  rowid[3] = 81; rowid[4] = 108; rowid[5] = 135; rowid[6] = 162; rowid[7] = 189;
}

// ---- kernel C (f16 gathers): t in [3,8) + prefix build ----
__global__ __launch_bounds__(256) void fused_main_f16_kernel(
    const int* __restrict__ tokens,
    float* __restrict__ ws,
    const float* __restrict__ W1, const float* __restrict__ W2,
    const float* __restrict__ Wo, float* __restrict__ out) {
  __shared__ h8 sW1T[H * 4];   // 4 KB
  __shared__ h8 sW2[H * 4];    // 4 KB
  __shared__ h8 sWoT[V * 4];   // 1.7 KB
  stage_weights(W1, W2, Wo, sW1T, sW2, sWoT);

  h2 o2[16];
  float* dst;
  if (blockIdx.x < MAIN_BLOCKS) {
    const int idx = blockIdx.x * 256 + threadIdx.x;   // [0, 5*BTOT), exact
    const int t = 3 + (idx >> 17);                    // wave-uniform
    const int b = idx & (BTOT - 1);
    const int4 ta = *(const int4*)(tokens + b * T);
    const int4 tb = *(const int4*)(tokens + b * T + 4);
    int rowid[T];
    rowid[0] = ta.x;       rowid[1] = 27 + ta.y;
    rowid[2] = 54 + ta.z;  rowid[3] = 81 + ta.w;
    rowid[4] = 108 + tb.x; rowid[5] = 135 + tb.y;
    rowid[6] = 162 + tb.z; rowid[7] = 189 + tb.w;
    attn_ln1_f16(t, rowid, ws, o2);
    dst = out + (long long)(b * T + t) * V;
  } else {
    const int i = (blockIdx.x - MAIN_BLOCKS) * 256 + threadIdx.x;
    if (i >= NPRE) return;
    int t;
    int rowid[T];
    decode_prefix(i, t, rowid);
    attn_ln1_f16(t, rowid, ws, o2);
    dst = ws + WS_P + i * V;
  }
  mlp_tail(o2, sW1T, sW2, sWoT, dst);
}

// ---- kernel C (R14, f32 gathers): safety net ----
__global__ __launch_bounds__(256) void fused_main_lds_kernel(
    const int* __restrict__ tokens,
    float* __restrict__ ws,
    const float* __restrict__ W1, const float* __restrict__ W2,
    const float* __restrict__ Wo, float* __restrict__ out) {
  __shared__ h8 sW1T[H * 4];
  __shared__ h8 sW2[H * 4];
  __shared__ h8 sWoT[V * 4];
  stage_weights(W1, W2, Wo, sW1T, sW2, sWoT);

  h2 o2[16];
  float* dst;
  if (blockIdx.x < MAIN_BLOCKS) {
    const int idx = blockIdx.x * 256 + threadIdx.x;
    const int t = 3 + (idx >> 17);
    const int b = idx & (BTOT - 1);
    const int4 ta = *(const int4*)(tokens + b * T);
    const int4 tb = *(const int4*)(tokens + b * T + 4);
    int rowid[T];
    rowid[0] = ta.x;       rowid[1] = 27 + ta.y;
    rowid[2] = 54 + ta.z;  rowid[3] = 81 + ta.w;
    rowid[4] = 108 + tb.x; rowid[5] = 135 + tb.y;
    rowid[6] = 162 + tb.z; rowid[7] = 189 + tb.w;
    attn_ln1_f32(t, rowid, ws, o2);
    dst = out + (long long)(b * T + t) * V;
  } else {
    const int i = (blockIdx.x - MAIN_BLOCKS) * 256 + threadIdx.x;
    if (i >= NPRE) return;
    int t;
    int rowid[T];
    decode_prefix(i, t, rowid);
    attn_ln1_f32(t, rowid, ws, o2);
    dst = ws + WS_P + i * V;
  }
  mlp_tail(o2, sW1T, sW2, sWoT, dst);
}

// ---- kernel G: gather t<=2 rows; thread per (b, r), r in [0,81) ----
__global__ __launch_bounds__(256) void gather_kernel(
    const int* __restrict__ tokens,
    const float* __restrict__ ws,
    float* __restrict__ out) {
  const int idx = blockIdx.x * 256 + threadIdx.x;   // [0, BTOT*81), exact
  const int b = idx / 81;
  const int r = idx - b * 81;
  const int t = r / 27;
  const int j = r - t * 27;
  const int t0 = tokens[b * T + 0];
  const int t1 = tokens[b * T + 1];
  const int t2 = tokens[b * T + 2];
  const int p01 = t0 * 27 + t1;
  const int pi = (t == 0) ? t0
               : (t == 1) ? (NPRE0 + p01)
                          : (NPRE0 + NPRE1 + p01 * 27 + t2);
  out[(long long)b * (T * V) + r] = ws[WS_P + pi * V + j];
}

// ---- fallback: all rows, thread per row (f32 gathers) ----
__global__ __launch_bounds__(256) void mini_kernel_all(
    const int* __restrict__ tokens,
    const float* __restrict__ ws,
    const float* __restrict__ W1, const float* __restrict__ W2,
    const float* __restrict__ Wo, float* __restrict__ out) {
  __shared__ h8 sW1T[H * 4];
  __shared__ h8 sW2[H * 4];
  __shared__ h8 sWoT[V * 4];
  stage_weights(W1, W2, Wo, sW1T, sW2, sWoT);

  const int r = blockIdx.x * 256 + threadIdx.x;
  const int b = r >> 3;
  const int t = r & 7;
  const int4 ta = *(const int4*)(tokens + b * T);
  const int4 tb = *(const int4*)(tokens + b * T + 4);
  int rowid[T];
  rowid[0] = ta.x;       rowid[1] = 27 + ta.y;
  rowid[2] = 54 + ta.z;  rowid[3] = 81 + ta.w;
  rowid[4] = 108 + tb.x; rowid[5] = 135 + tb.y;
  rowid[6] = 162 + tb.z; rowid[7] = 189 + tb.w;
  h2 o2[16];
  attn_ln1_f32(t, rowid, ws, o2);
  mlp_tail(o2, sW1T, sW2, sWoT, out + (long long)r * V);
}

extern "C" void kernel_launch(void* const* d_in, const int* in_sizes, int n_in,
                              void* d_out, int out_size, void* d_ws, size_t ws_size,
                              hipStream_t stream) {
  const int*   tokens  = (const int*)d_in[0];
  const float* tok_emb = (const float*)d_in[1];
  const float* pos_emb = (const float*)d_in[2];
  const float* Wq      = (const float*)d_in[3];
  const float* Wk      = (const float*)d_in[4];
  const float* Wv      = (const float*)d_in[5];
  const float* W1      = (const float*)d_in[6];
  const float* W2      = (const float*)d_in[7];
  const float* Wout    = (const float*)d_in[8];
  float* ws = (float*)d_ws;
  float* out = (float*)d_out;

  const int wf16 = (ws_size >= WS_NEED_F16) ? 1 : 0;
  hipLaunchKernelGGL(build_rows_kernel, dim3((NROW * D + 255) / 256), dim3(256), 0,
                     stream, tok_emb, pos_emb, Wq, Wk, Wv, ws, wf16);
  hipLaunchKernelGGL(build_sc_kernel, dim3((NSC + 255) / 256), dim3(256), 0, stream, ws);

  if (wf16) {
    hipLaunchKernelGGL(fused_main_f16_kernel, dim3(MAIN_BLOCKS + PRE_BLOCKS),
                       dim3(256), 0, stream, tokens, ws, W1, W2, Wout, out);
    hipLaunchKernelGGL(gather_kernel, dim3((BTOT * 81) / 256), dim3(256), 0, stream,
                       tokens, ws, out);
  } else if (ws_size >= WS_NEED_BIG) {
    hipLaunchKernelGGL(fused_main_lds_kernel, dim3(MAIN_BLOCKS + PRE_BLOCKS),
                       dim3(256), 0, stream, tokens, ws, W1, W2, Wout, out);
    hipLaunchKernelGGL(gather_kernel, dim3((BTOT * 81) / 256), dim3(256), 0, stream,
                       tokens, ws, out);
  } else {
    hipLaunchKernelGGL(mini_kernel_all, dim3((BTOT * T) / 256), dim3(256), 0,
                       stream, tokens, ws, W1, W2, Wout, out);
  }
}